// Round 10
// baseline (542.874 us; speedup 1.0000x reference)
//
#include <hip/hip_runtime.h>
#include <hip/hip_bf16.h>
#include <math.h>

#define NROW 32768   // B*N
#define CVC  512
#define T77  77
#define BT   616     // B*T
#define HHC  8
#define DHC  64

typedef __attribute__((ext_vector_type(8))) short bf16x8;
typedef __attribute__((ext_vector_type(4))) float f32x4;

__device__ __forceinline__ void gload_lds16(const void* g, void* l) {
  __builtin_amdgcn_global_load_lds(
      (__attribute__((address_space(1))) void*)g,
      (__attribute__((address_space(3))) void*)l, 16, 0, 0);
}

__device__ __forceinline__ float wave_reduce_sum(float v) {
  #pragma unroll
  for (int s = 32; s > 0; s >>= 1) v += __shfl_xor(v, s, 64);
  return v;
}

// Per-row LN1 stats + x_rms + gate pre-act + x in bf16.
// Wave-per-row: 64 lanes x 8 f32 (two float4 loads), shfl-only reductions, no barriers.
__global__ __launch_bounds__(256)
void stats1_kernel(const float* __restrict__ visual, const float* __restrict__ g,
                   const float* __restrict__ b, const float* __restrict__ Wg,
                   const float* __restrict__ bg,
                   float* __restrict__ mean1, float* __restrict__ rstd1,
                   float* __restrict__ xrms, float* __restrict__ gpre,
                   __hip_bfloat16* __restrict__ xbf) {
  const int lane = threadIdx.x & 63;
  const int row  = blockIdx.x * 4 + (threadIdx.x >> 6);
  const float* vr = visual + (size_t)row * CVC + lane * 8;
  float4 va = *(const float4*)vr;
  float4 vb = *(const float4*)(vr + 4);
  float v[8] = {va.x, va.y, va.z, va.w, vb.x, vb.y, vb.z, vb.w};
  float s = 0.f;
  #pragma unroll
  for (int i = 0; i < 8; i++) s += v[i];
  float m = wave_reduce_sum(s) * (1.0f / CVC);
  float s2 = 0.f;
  #pragma unroll
  for (int i = 0; i < 8; i++) { float d = v[i] - m; s2 += d * d; }
  float rs = rsqrtf(wave_reduce_sum(s2) * (1.0f / CVC) + 1e-5f);
  const float4 g0 = *(const float4*)(g + lane * 8), g1v = *(const float4*)(g + lane * 8 + 4);
  const float4 b0 = *(const float4*)(b + lane * 8), b1v = *(const float4*)(b + lane * 8 + 4);
  const float4 w0 = *(const float4*)(Wg + lane * 8), w1 = *(const float4*)(Wg + lane * 8 + 4);
  float gg[8] = {g0.x, g0.y, g0.z, g0.w, g1v.x, g1v.y, g1v.z, g1v.w};
  float bb[8] = {b0.x, b0.y, b0.z, b0.w, b1v.x, b1v.y, b1v.z, b1v.w};
  float ww[8] = {w0.x, w0.y, w0.z, w0.w, w1.x, w1.y, w1.z, w1.w};
  float x[8], sx2 = 0.f, sg = 0.f;
  union { bf16x8 v8; __hip_bfloat16 h[8]; } u;
  #pragma unroll
  for (int i = 0; i < 8; i++) {
    x[i] = (v[i] - m) * rs * gg[i] + bb[i];
    sx2 += x[i] * x[i];
    sg  += x[i] * ww[i];
    u.h[i] = __float2bfloat16(x[i]);
  }
  *(bf16x8*)(xbf + (size_t)row * CVC + lane * 8) = u.v8;
  sx2 = wave_reduce_sum(sx2);
  sg  = wave_reduce_sum(sg);
  if (lane == 0) {
    mean1[row] = m; rstd1[row] = rs;
    xrms[row] = sqrtf(sx2 * (1.0f / CVC)) + 1e-6f;
    gpre[row] = sg + bg[0];
  }
}

// W[K][N] f32 -> Wt[N][K] bf16 (tiled transpose)
__global__ void convT_kernel(const float* __restrict__ W, __hip_bfloat16* __restrict__ Wt,
                             int K, int N) {
  __shared__ float t[32][33];
  int n0 = blockIdx.x * 32, k0 = blockIdx.y * 32;
  int tx = threadIdx.x, ty = threadIdx.y;   // 32, 8
  #pragma unroll
  for (int i = 0; i < 32; i += 8) t[ty + i][tx] = W[(size_t)(k0 + ty + i) * N + n0 + tx];
  __syncthreads();
  #pragma unroll
  for (int i = 0; i < 32; i += 8)
    Wt[(size_t)(n0 + ty + i) * K + k0 + tx] = __float2bfloat16(t[tx][ty + i]);
}

// MFMA bf16 GEMM: C[M,N] = A[M,K] @ Bt[N,K]^T + bias
// 256x256 tile, BK=64, 8 waves (2x4). m201-style 8-PHASE schedule: 2 K-tiles per
// iteration, one C-quadrant (16 MFMA) per phase, 1 half-tile staged per phase,
// counted vmcnt(4) ONLY at phases 4 and 8 (vmcnt(0) on last iteration).
// Staging cadence (derived ledger, tiles u=2i, v=2i+1):
//   ph1,2: A0,A1(v)->buf1 | ph3,4: B0,B1(u+2)->buf0 | ph5,6: A0,A1(u+2)->buf0
//   ph7,8: B0,B1(v+2)->buf1
// Slot frees: B(tile) after its Q2 phase, A(tile) after its Q3 phase — all 8
// stages land in free slots; every half forced landed by a vmcnt(4) before its
// first read (ph4 forces A(v)+B(v); ph8 forces A(u+2)+B(u+2)).
// T2 XOR-swizzled LDS (inverse swizzle on global source), T5 setprio per quadrant.
// EPI 0: f32 store (LDS-coalesced)  | 1: sigmoid-gelu -> bf16 (LDS-coalesced)
// EPI 2: out += v (LDS-coalesced float4 RMW)
template<int EPI>
__global__ __launch_bounds__(512, 2)
void mfma_gemm(const __hip_bfloat16* __restrict__ A, const __hip_bfloat16* __restrict__ Bt,
               const float* __restrict__ bias, float* __restrict__ out,
               __hip_bfloat16* __restrict__ outbf, int M, int N, int K) {
  __shared__ __align__(16) char lds[131072];   // A: 2 x 32KB @0, B: 2 x 32KB @64KB
  const int tid = threadIdx.x;
  const int lane = tid & 63;
  const int wid  = tid >> 6;

  // XCD-aware bijective swizzle (all launches have nwg % 8 == 0)
  const int nwg  = gridDim.x * gridDim.y;
  const int orig = blockIdx.y * gridDim.x + blockIdx.x;
  const int wg   = (orig & 7) * (nwg >> 3) + (orig >> 3);
  const int bx = wg % gridDim.x;
  const int by = wg / gridDim.x;
  const int bm = by * 256, bn = bx * 256;

  const int wm = wid >> 2, wn = wid & 3;       // wave -> 128x64 sub-tile
  const int lrow = lane & 15, kq = lane >> 4;

  f32x4 acc[8][4] = {};

  // ---- staging: per gload, lane covers row r_in (of 8) x swizzled 16B block ----
  const int r_in = lane >> 3;                  // 0..7
  const int cblk = (lane & 7) ^ r_in;          // inverse swizzle on global source
  const __hip_bfloat16* gA = A  + (size_t)(bm + r_in) * K + cblk * 8;
  const __hip_bfloat16* gB = Bt + (size_t)(bn + r_in) * K + cblk * 8;
  char* ldsA = lds;
  char* ldsB = lds + 65536;

  auto stageA = [&](int buf, int k0, int half) {
    #pragma unroll
    for (int j = 0; j < 2; j++) {
      int R0 = half * 128 + wid * 16 + j * 8;
      gload_lds16(gA + (size_t)R0 * K + k0, ldsA + buf * 32768 + R0 * 128);
    }
  };
  auto stageB = [&](int buf, int k0, int half) {
    #pragma unroll
    for (int j = 0; j < 2; j++) {
      int R0 = half * 128 + wid * 16 + j * 8;
      gload_lds16(gB + (size_t)R0 * K + k0, ldsB + buf * 32768 + R0 * 128);
    }
  };

  // ---- swizzled LDS reads: blk = (kk*4+kq) ^ (row&7), row&7 == lrow&7 ----
  const int swz = lrow & 7;
  auto ldA = [&](int buf, int m, int kk) -> bf16x8 {
    int r = wm * 128 + m * 16 + lrow;
    int blk = (kk * 4 + kq) ^ swz;
    return *(const bf16x8*)(ldsA + buf * 32768 + r * 128 + blk * 16);
  };
  auto ldB = [&](int buf, int n, int kk) -> bf16x8 {
    int r = wn * 64 + n * 16 + lrow;
    int blk = (kk * 4 + kq) ^ swz;
    return *(const bf16x8*)(ldsB + buf * 32768 + r * 128 + blk * 16);
  };

  const int NT  = K >> 6;
  const int NIT = NT >> 1;
  // prologue: tile0 all 4 halves + tile1 B halves (12 loads/wave), keep B(1) in flight
  stageB(0, 0, 0); stageB(0, 0, 1);
  stageA(0, 0, 0); stageA(0, 0, 1);
  stageB(1, 64, 0); stageB(1, 64, 1);
  asm volatile("s_waitcnt vmcnt(4)" ::: "memory");
  __builtin_amdgcn_s_barrier();

  bf16x8 af[4][2], bf01[2][2], bf23[2][2];

  auto rdAf = [&](int buf, int mb) {
    #pragma unroll
    for (int m = 0; m < 4; m++) { af[m][0] = ldA(buf, mb + m, 0); af[m][1] = ldA(buf, mb + m, 1); }
  };
  auto rdB01 = [&](int buf) {
    #pragma unroll
    for (int n = 0; n < 2; n++) { bf01[n][0] = ldB(buf, n, 0); bf01[n][1] = ldB(buf, n, 1); }
  };
  auto rdB23 = [&](int buf) {
    #pragma unroll
    for (int n = 0; n < 2; n++) { bf23[n][0] = ldB(buf, n + 2, 0); bf23[n][1] = ldB(buf, n + 2, 1); }
  };

#define QUAD(MB, NB, BFX) \
  __builtin_amdgcn_s_setprio(1); \
  _Pragma("unroll") \
  for (int m = 0; m < 4; m++) { \
    _Pragma("unroll") \
    for (int n = 0; n < 2; n++) { \
      acc[(MB)+m][(NB)+n] = __builtin_amdgcn_mfma_f32_16x16x32_bf16(af[m][0], BFX[n][0], acc[(MB)+m][(NB)+n], 0, 0, 0); \
      acc[(MB)+m][(NB)+n] = __builtin_amdgcn_mfma_f32_16x16x32_bf16(af[m][1], BFX[n][1], acc[(MB)+m][(NB)+n], 0, 0, 0); \
    } \
  } \
  __builtin_amdgcn_s_setprio(0);
#define BARR  __builtin_amdgcn_s_barrier()
#define LGKM0 asm volatile("s_waitcnt lgkmcnt(0)" ::: "memory")
#define LGKM8 asm volatile("s_waitcnt lgkmcnt(8)" ::: "memory")

  for (int i = 0; i < NIT; ++i) {
    const int u   = 2 * i;
    const bool nl = (i + 1 < NIT);     // not-last iteration
    const int kv  = (u + 1) << 6;
    const int ku2 = (u + 2) << 6;
    const int kv2 = (u + 3) << 6;

    // ======== tile u (buf 0) ========
    // ph1: 12 reads; stage A0(v)
    rdAf(0, 0); rdB01(0);
    stageA(1, kv, 0);
    LGKM8; BARR; LGKM0; QUAD(0, 0, bf01); BARR;
    // ph2: 4 reads; stage A1(v)
    rdB23(0);
    stageA(1, kv, 1);
    BARR; LGKM0; QUAD(0, 2, bf23); BARR;
    // ph3: 8 reads; stage B0(u+2)
    rdAf(0, 4);
    if (nl) stageB(0, ku2, 0);
    BARR; LGKM0; QUAD(4, 0, bf01); BARR;
    // ph4: stage B1(u+2); counted vmcnt (forces all of tile v landed)
    if (nl) { stageB(0, ku2, 1); asm volatile("s_waitcnt vmcnt(4)" ::: "memory"); }
    else    { asm volatile("s_waitcnt vmcnt(0)" ::: "memory"); }
    BARR; QUAD(4, 2, bf23); BARR;

    // ======== tile v (buf 1) ========
    // ph5: 12 reads; stage A0(u+2)
    rdAf(1, 0); rdB01(1);
    if (nl) stageA(0, ku2, 0);
    LGKM8; BARR; LGKM0; QUAD(0, 0, bf01); BARR;
    // ph6: 4 reads; stage A1(u+2)
    rdB23(1);
    if (nl) stageA(0, ku2, 1);
    BARR; LGKM0; QUAD(0, 2, bf23); BARR;
    // ph7: 8 reads; stage B0(v+2)
    rdAf(1, 4);
    if (nl) stageB(1, kv2, 0);
    BARR; LGKM0; QUAD(4, 0, bf01); BARR;
    // ph8: stage B1(v+2); counted vmcnt (forces all of tile u+2 landed)
    if (nl) { stageB(1, kv2, 1); asm volatile("s_waitcnt vmcnt(4)" ::: "memory"); }
    else    { asm volatile("s_waitcnt vmcnt(0)" ::: "memory"); }
    BARR; QUAD(4, 2, bf23); BARR;
  }
#undef QUAD
#undef BARR
#undef LGKM0
#undef LGKM8

  // epilogue: fragment row = kq*4 + rg, col = lrow
  const int c0 = bn + wn * 64 + lrow;
  if (EPI == 1) {
    // bf16 output via per-wave 16KB LDS (kq-swizzled, conflict-free), 16B/lane stores.
    // gelu: sigmoid form, max |err vs exact| ~5e-4 << bf16 quantization of H.
    __syncthreads();                    // K-loop LDS fully dead
    char* eb = lds + wid * 16384;       // 128 rows x 128B
    #pragma unroll
    for (int n = 0; n < 4; n++) {
      float bval = bias[c0 + n * 16];
      #pragma unroll
      for (int m = 0; m < 8; m++) {
        #pragma unroll
        for (int rg = 0; rg < 4; rg++) {
          int lr  = m * 16 + kq * 4 + rg;               // (lr>>2)&3 == kq
          int lcb = (n * 32 + lrow * 2) ^ (kq << 5);    // swizzled byte-in-row
          float v = acc[m][n][rg] + bval;
          float ge = v / (1.0f + __expf(v * (-1.5957691216f - 0.0713548162f * v * v)));
          *(__hip_bfloat16*)(eb + lr * 128 + lcb) = __float2bfloat16(ge);
        }
      }
    }
    asm volatile("s_waitcnt lgkmcnt(0)" ::: "memory");  // wave-local LDS drain
    __builtin_amdgcn_sched_barrier(0);
    const int rr = lane >> 3, bb = lane & 7;
    #pragma unroll
    for (int it = 0; it < 16; it++) {
      int lr  = it * 8 + rr;
      int lcb = (bb << 4) ^ (((lr >> 2) & 3) << 5);
      uint4 v = *(const uint4*)(eb + lr * 128 + lcb);
      size_t go = (size_t)(bm + wm * 128 + lr) * N + (bn + wn * 64 + bb * 8);
      *(uint4*)(&outbf[go]) = v;
    }
  } else {
    // f32 output via per-wave 16KB LDS, two 64-row half-passes (f32 tile = 32KB).
    // Write: bank = ((n*16+lrow)^(kq*16))%32 -> 2-way max (free). Read: float4 rows.
    __syncthreads();                    // K-loop LDS fully dead
    char* eb = lds + wid * 16384;       // 64 rows x 256B
    const int rr = lane >> 4, bb = lane & 15;
    #pragma unroll
    for (int half = 0; half < 2; half++) {
      if (half) {                        // half0 reads done before overwrite
        asm volatile("s_waitcnt lgkmcnt(0)" ::: "memory");
        __builtin_amdgcn_sched_barrier(0);
      }
      #pragma unroll
      for (int n = 0; n < 4; n++) {
        float bval = bias[c0 + n * 16];
        #pragma unroll
        for (int m = 0; m < 4; m++) {
          #pragma unroll
          for (int rg = 0; rg < 4; rg++) {
            int lr  = m * 16 + kq * 4 + rg;             // 0..63
            int byo = (n * 64 + lrow * 4) ^ (kq << 6);  // swizzled byte-in-row
            *(float*)(eb + lr * 256 + byo) = acc[half * 4 + m][n][rg] + bval;
          }
        }
      }
      asm volatile("s_waitcnt lgkmcnt(0)" ::: "memory");
      __builtin_amdgcn_sched_barrier(0);
      #pragma unroll
      for (int it = 0; it < 16; it++) {
        int lr  = it * 4 + rr;
        int byo = (bb * 16) ^ (((lr >> 2) & 3) << 6);
        float4 v4 = *(const float4*)(eb + lr * 256 + byo);
        size_t go = (size_t)(bm + wm * 128 + half * 64 + lr) * N + (bn + wn * 64 + bb * 4);
        if (EPI == 0) {
          *(float4*)(&out[go]) = v4;
        } else {
          const float4 o = *(const float4*)(&out[go]);
          v4.x += o.x; v4.y += o.y; v4.z += o.z; v4.w += o.w;
          *(float4*)(&out[go]) = v4;
        }
      }
    }
  }
}

// Fused K/V projection GEMM (one launch, 160 blocks): by<10 -> K, else V
__global__ void kv2_gemm(const float* __restrict__ A,
                         const float* __restrict__ Wk, const float* __restrict__ bk,
                         const float* __restrict__ Wv, const float* __restrict__ bv,
                         float* __restrict__ KF, float* __restrict__ VF,
                         int M, int K, int N) {
  __shared__ float As[16][68];
  __shared__ float Bs[16][68];
  const bool isV = blockIdx.y >= 10;
  const float* W    = isV ? Wv : Wk;
  const float* bias = isV ? bv : bk;
  float* out        = isV ? VF : KF;
  int tid = threadIdx.x;
  int bm = (isV ? blockIdx.y - 10 : blockIdx.y) * 64, bn = blockIdx.x * 64;
  int ty = tid >> 4, tx = tid & 15;
  float acc[4][4] = {};
  for (int k0 = 0; k0 < K; k0 += 16) {
    #pragma unroll
    for (int i = 0; i < 4; i++) {
      int idx = tid + i * 256;
      int mm = idx >> 4, kk = idx & 15;
      int row = bm + mm;
      As[kk][mm] = (row < M) ? A[(size_t)row * K + k0 + kk] : 0.f;
    }
    #pragma unroll
    for (int i = 0; i < 4; i++) {
      int idx = tid + i * 256;
      int kk = idx >> 6, nn = idx & 63;
      Bs[kk][nn] = W[(size_t)(k0 + kk) * N + bn + nn];
    }
    __syncthreads();
    #pragma unroll
    for (int kk = 0; kk < 16; kk++) {
      float4 av = *(const float4*)&As[kk][ty * 4];
      float4 bv4 = *(const float4*)&Bs[kk][tx * 4];
      float a_[4] = {av.x, av.y, av.z, av.w};
      float b_[4] = {bv4.x, bv4.y, bv4.z, bv4.w};
      #pragma unroll
      for (int i = 0; i < 4; i++)
        #pragma unroll
        for (int j = 0; j < 4; j++)
          acc[i][j] = fmaf(a_[i], b_[j], acc[i][j]);
    }
    __syncthreads();
  }
  #pragma unroll
  for (int i = 0; i < 4; i++) {
    int row = bm + ty * 4 + i;
    if (row >= M) continue;
    #pragma unroll
    for (int j = 0; j < 4; j++) {
      int col = bn + tx * 4 + j;
      out[(size_t)row * N + col] = acc[i][j] + bias[col];
    }
  }
}

// L2 normalize rows of buf -> bf16 out. Wave-per-row, shfl reduction, no barriers.
__global__ __launch_bounds__(256)
void l2norm_kernel(const float* __restrict__ buf, __hip_bfloat16* __restrict__ qbf) {
  const int lane = threadIdx.x & 63;
  const int row  = blockIdx.x * 4 + (threadIdx.x >> 6);
  const float* p = buf + (size_t)row * CVC + lane * 8;
  float4 va = *(const float4*)p;
  float4 vb = *(const float4*)(p + 4);
  float v[8] = {va.x, va.y, va.z, va.w, vb.x, vb.y, vb.z, vb.w};
  float s = 0.f;
  #pragma unroll
  for (int i = 0; i < 8; i++) s += v[i] * v[i];
  s = wave_reduce_sum(s);
  float inv = 1.0f / fmaxf(sqrtf(s), 1e-6f);
  union { bf16x8 v8; __hip_bfloat16 h[8]; } u;
  #pragma unroll
  for (int i = 0; i < 8; i++) u.h[i] = __float2bfloat16(v[i] * inv);
  *(bf16x8*)(qbf + (size_t)row * CVC + lane * 8) = u.v8;
}

// Wave-per-row K-norm + pad detection (616 rows = 154 blocks x 4 waves)
__global__ __launch_bounds__(256)
void knorm_kernel(float* __restrict__ kf, const float* __restrict__ text,
                  int* __restrict__ pad) {
  const int lane = threadIdx.x & 63;
  const int row  = blockIdx.x * 4 + (threadIdx.x >> 6);
  float* p = kf + (size_t)row * CVC + lane * 8;
  const float* tx = text + (size_t)row * CVC + lane * 8;
  float4 va = *(const float4*)p;
  float4 vb = *(const float4*)(p + 4);
  float4 ta = *(const float4*)tx;
  float4 tb = *(const float4*)(tx + 4);
  float v[8] = {va.x, va.y, va.z, va.w, vb.x, vb.y, vb.z, vb.w};
  float t[8] = {ta.x, ta.y, ta.z, ta.w, tb.x, tb.y, tb.z, tb.w};
  float s = 0.f, a = 0.f;
  #pragma unroll
  for (int i = 0; i < 8; i++) { s += v[i] * v[i]; a += fabsf(t[i]); }
  s = wave_reduce_sum(s);
  a = wave_reduce_sum(a);
  float inv = 1.0f / fmaxf(sqrtf(s), 1e-6f);
  float4 o0 = {v[0] * inv, v[1] * inv, v[2] * inv, v[3] * inv};
  float4 o1 = {v[4] * inv, v[5] * inv, v[6] * inv, v[7] * inv};
  *(float4*)p = o0;
  *(float4*)(p + 4) = o1;
  if (lane == 0) pad[row] = (a <= 1e-6f) ? 1 : 0;
}

// Repack normalized K into per-(b,h) MFMA B^T tiles: KBF[b][h][80][64] bf16, t>=77 zero
__global__ void kbf_kernel(const float* __restrict__ kf, __hip_bfloat16* __restrict__ kbf) {
  int bh = blockIdx.x;                 // 64 blocks
  int b = bh >> 3, h = bh & 7;
  int tid = threadIdx.x;
  for (int i = tid; i < 80 * 64; i += 256) {
    int t = i >> 6, d = i & 63;
    float v = (t < T77) ? kf[(size_t)(b * T77 + t) * CVC + h * DHC + d] : 0.0f;
    kbf[(size_t)bh * (80 * 64) + i] = __float2bfloat16(v);
  }
}

// Attention phase A: SIM[row][h][t] = q_row_h . k_t_h via MFMA (raw dot, no scale)
__global__ __launch_bounds__(256)
void simA_kernel(const __hip_bfloat16* __restrict__ qbf, const __hip_bfloat16* __restrict__ kbf,
                 float* __restrict__ sim) {
  const int tid = threadIdx.x;
  const int wid = tid >> 6, lane = tid & 63;
  const int r0 = blockIdx.x * 64 + wid * 16;     // 16 rows per wave
  const int b = (blockIdx.x * 64) >> 12;         // 4096 rows per batch
  const int lrow = lane & 15, kq = lane >> 4;
  const __hip_bfloat16* qrow = qbf + (size_t)(r0 + lrow) * CVC;
  for (int h = 0; h < HHC; h++) {
    const __hip_bfloat16* kb = kbf + (size_t)(b * 8 + h) * (80 * 64);
    f32x4 acc[5] = {};
    #pragma unroll
    for (int ks = 0; ks < 2; ks++) {
      bf16x8 af = *(const bf16x8*)(qrow + h * DHC + ks * 32 + kq * 8);
      #pragma unroll
      for (int n = 0; n < 5; n++) {
        bf16x8 bf = *(const bf16x8*)(kb + (size_t)(n * 16 + lrow) * DHC + ks * 32 + kq * 8);
        acc[n] = __builtin_amdgcn_mfma_f32_16x16x32_bf16(af, bf, acc[n], 0, 0, 0);
      }
    }
    // C layout: row = r0 + kq*4 + reg, col = n*16 + lrow
    #pragma unroll
    for (int n = 0; n < 5; n++)
      #pragma unroll
      for (int rg = 0; rg < 4; rg++)
        sim[(size_t)(r0 + kq * 4 + rg) * 640 + h * 80 + n * 16 + lrow] = acc[n][rg];
  }
}

// Attention phase B: per (row,head) thread streams its 80-entry sim row (coalesced),
// top-5 / softmax / nucleus / entropy / conf, then cooperative sparse PV -> bf16.
__global__ __launch_bounds__(256)
void attnB_kernel(const float* __restrict__ sim, const float* __restrict__ vf,
                  const int* __restrict__ pad, const float* __restrict__ ls,
                  float* __restrict__ conf_out, __hip_bfloat16* __restrict__ abf) {
  __shared__ float spr[32][HHC][5];
  __shared__ int   sti[32][HHC][5];
  __shared__ float sconf[256];
  __shared__ float sbias[80];
  const int tid = threadIdx.x;
  const int r = tid >> 3, h = tid & 7;
  const int r0 = blockIdx.x * 32;
  const int b = r0 >> 12;
  const float lsv = fminf(fmaxf(ls[0], -2.0f), 2.0f);
  const float scale = expf(lsv) * 0.125f;   // / sqrt(64)

  if (tid < 80) sbias[tid] = (tid < T77 && !pad[b * T77 + tid]) ? 0.0f : -INFINITY;
  __syncthreads();

  // stream 80 sim values (20 float4, contiguous per thread, coalesced per block)
  float t0 = -INFINITY, t1 = -INFINITY, t2 = -INFINITY, t3 = -INFINITY, t4 = -INFINITY;
  int   i0 = -1, i1 = -1, i2 = -1, i3 = -1, i4 = -1;
  const float4* simp = (const float4*)(sim + (size_t)(r0 + r) * 640 + h * 80);
  #pragma unroll
  for (int tt = 0; tt < 20; tt++) {
    float4 v4 = simp[tt];
    #pragma unroll
    for (int j = 0; j < 4; j++) {
      int t = tt * 4 + j;
      float sv = (j == 0 ? v4.x : j == 1 ? v4.y : j == 2 ? v4.z : v4.w);
      float s = sv * scale + sbias[t];
      if (s > t4) {
        t4 = s; i4 = t;
        if (t4 > t3) { float f = t3; t3 = t4; t4 = f; int x = i3; i3 = i4; i4 = x; }
        if (t3 > t2) { float f = t2; t2 = t3; t3 = f; int x = i2; i2 = i3; i3 = x; }
        if (t2 > t1) { float f = t1; t1 = t2; t2 = f; int x = i1; i1 = i2; i2 = x; }
        if (t1 > t0) { float f = t0; t0 = t1; t1 = f; int x = i0; i0 = i1; i1 = x; }
      }
    }
  }

  // softmax over top-5
  float e0 = (t0 == -INFINITY) ? 0.f : expf(t0 - t0);
  float e1 = (t1 == -INFINITY) ? 0.f : expf(t1 - t0);
  float e2 = (t2 == -INFINITY) ? 0.f : expf(t2 - t0);
  float e3 = (t3 == -INFINITY) ? 0.f : expf(t3 - t0);
  float e4 = (t4 == -INFINITY) ? 0.f : expf(t4 - t0);
  float invs = 1.0f / (e0 + e1 + e2 + e3 + e4);
  float p0 = e0 * invs, p1 = e1 * invs, p2 = e2 * invs, p3 = e3 * invs, p4 = e4 * invs;
  // nucleus: inclusive cumsum <= 0.9, top-1 forced
  float c1 = p0 + p1, c2 = c1 + p2, c3 = c2 + p3, c4 = c3 + p4;
  bool k1 = (c1 <= 0.9f), k2 = (c2 <= 0.9f), k3 = (c3 <= 0.9f), k4 = (c4 <= 0.9f);
  float skeep = p0 + (k1 ? p1 : 0.f) + (k2 ? p2 : 0.f) + (k3 ? p3 : 0.f) + (k4 ? p4 : 0.f);
  float rn = 1.0f / fmaxf(skeep, 1e-6f);
  float w0 = p0 * rn, w1 = k1 ? p1 * rn : 0.f, w2 = k2 ? p2 * rn : 0.f,
        w3 = k3 ? p3 * rn : 0.f, w4 = k4 ? p4 * rn : 0.f;
  int nnz = (w0 > 0.f) + (w1 > 0.f) + (w2 > 0.f) + (w3 > 0.f) + (w4 > 0.f);
  float ent = 0.f;
  {
    float pc;
    pc = fmaxf(w0, 1e-8f); ent -= pc * logf(pc);
    pc = fmaxf(w1, 1e-8f); ent -= pc * logf(pc);
    pc = fmaxf(w2, 1e-8f); ent -= pc * logf(pc);
    pc = fmaxf(w3, 1e-8f); ent -= pc * logf(pc);
    pc = fmaxf(w4, 1e-8f); ent -= pc * logf(pc);
  }
  ent += (float)(T77 - 5) * 1.8420681e-7f;   // 72 zero entries at pc=1e-8
  float denom = logf(fmaxf(fmaxf((float)nnz, 1.0f), 2.0f));
  ent /= denom;
  float confh = fminf(fmaxf(w0 * (1.0f - ent), 0.f), 1.f);

  spr[r][h][0] = w0; spr[r][h][1] = w1; spr[r][h][2] = w2; spr[r][h][3] = w3; spr[r][h][4] = w4;
  sti[r][h][0] = i0; sti[r][h][1] = i1; sti[r][h][2] = i2; sti[r][h][3] = i3; sti[r][h][4] = i4;
  sconf[tid] = confh;
  __syncthreads();

  if (tid < 32) {
    float s = 0.f;
    #pragma unroll
    for (int j = 0; j < 8; j++) s += sconf[tid * 8 + j];
    conf_out[r0 + tid] = s * 0.125f;
  }

  // cooperative sparse PV: wave-uniform (row,head) -> coalesced v loads
  #pragma unroll
  for (int it = 0; it < 64; it++) {
    int idx = tid + it * 256;
    int rr = idx >> 9, c = idx & 511, hh = c >> 6;
    float a = 0.f;
    #pragma unroll
    for (int i = 0; i < 5; i++) {
      float pr = spr[rr][hh][i]; int t = sti[rr][hh][i];
      if (pr > 0.f && t >= 0) a = fmaf(pr, vf[((size_t)(b * T77 + t)) * CVC + c], a);
    }
    abf[(size_t)(r0 + rr) * CVC + c] = __float2bfloat16(a);
  }
}

// Trust region + gate + residual -> y (f32 out) AND LN2(y) in bf16.
// Wave-per-row, shfl reductions, no barriers.
__global__ __launch_bounds__(256)
void combine_kernel(const float* __restrict__ al1, const float* __restrict__ visual,
                    const float* __restrict__ m1, const float* __restrict__ r1,
                    const float* __restrict__ g1, const float* __restrict__ b1v,
                    const float* __restrict__ xrms, const float* __restrict__ gpre,
                    const float* __restrict__ conf, const float* __restrict__ alpha,
                    const float* __restrict__ g2, const float* __restrict__ b2v,
                    float* __restrict__ dout, __hip_bfloat16* __restrict__ ybf) {
  const int lane = threadIdx.x & 63;
  const int row  = blockIdx.x * 4 + (threadIdx.x >> 6);
  const float* ar = al1 + (size_t)row * CVC + lane * 8;
  float4 aa = *(const float4*)ar;
  float4 ab = *(const float4*)(ar + 4);
  float av[8] = {aa.x, aa.y, aa.z, aa.w, ab.x, ab.y, ab.z, ab.w};
  float s2 = 0.f;
  #pragma unroll
  for (int i = 0; i < 8; i++) s2 += av[i] * av[i];
  s2 = wave_reduce_sum(s2);
  float an = sqrtf(s2);
  float factor = fminf(0.5f * xrms[row] / fmaxf(an, 1e-6f), 1.0f);
  float gate = conf[row] / (1.0f + expf(-gpre[row]));
  float coef = alpha[0] * gate * factor;
  float mm = m1[row], rs = r1[row];
  const float* vr = visual + (size_t)row * CVC + lane * 8;
  float4 va = *(const float4*)vr;
  float4 vb = *(const float4*)(vr + 4);
  float v[8] = {va.x, va.y, va.z, va.w, vb.x, vb.y, vb.z, vb.w};
  const float4 ga = *(const float4*)(g1 + lane * 8), gb = *(const float4*)(g1 + lane * 8 + 4);
  const float4 ba = *(const float4*)(b1v + lane * 8), bb2 = *(const float4*)(b1v + lane * 8 + 4);
  float gg[8] = {ga.x, ga.y, ga.z, ga.w, gb.x, gb.y, gb.z, gb.w};
  float bbv[8] = {ba.x, ba.y, ba.z, ba.w, bb2.x, bb2.y, bb2.z, bb2.w};
  float y[8], sy = 0.f;
  #pragma unroll
  for (int i = 0; i < 8; i++) {
    float x = (v[i] - mm) * rs * gg[i] + bbv[i];
    y[i] = x + coef * av[i];
    sy += y[i];
  }
  float* orow = dout + (size_t)row * CVC + lane * 8;
  float4 o0 = {y[0], y[1], y[2], y[3]};
  float4 o1 = {y[4], y[5], y[6], y[7]};
  *(float4*)orow = o0;
  *(float4*)(orow + 4) = o1;
  float ym = wave_reduce_sum(sy) * (1.0f / CVC);
  float var = 0.f;
  #pragma unroll
  for (int i = 0; i < 8; i++) { float d = y[i] - ym; var += d * d; }
  var = wave_reduce_sum(var) * (1.0f / CVC);
  float rs2 = rsqrtf(var + 1e-5f);
  const float4 g2a = *(const float4*)(g2 + lane * 8), g2b = *(const float4*)(g2 + lane * 8 + 4);
  const float4 b2a = *(const float4*)(b2v + lane * 8), b2b = *(const float4*)(b2v + lane * 8 + 4);
  float g2v[8] = {g2a.x, g2a.y, g2a.z, g2a.w, g2b.x, g2b.y, g2b.z, g2b.w};
  float b2vv[8] = {b2a.x, b2a.y, b2a.z, b2a.w, b2b.x, b2b.y, b2b.z, b2b.w};
  union { bf16x8 v8; __hip_bfloat16 h[8]; } u;
  #pragma unroll
  for (int i = 0; i < 8; i++)
    u.h[i] = __float2bfloat16((y[i] - ym) * rs2 * g2v[i] + b2vv[i]);
  *(bf16x8*)(ybf + (size_t)row * CVC + lane * 8) = u.v8;
}

extern "C" void kernel_launch(void* const* d_in, const int* in_sizes, int n_in,
                              void* d_out, int out_size, void* d_ws, size_t ws_size,
                              hipStream_t stream) {
  const float* visual = (const float*)d_in[0];
  const float* text   = (const float*)d_in[1];
  const float* ln1_g  = (const float*)d_in[2];
  const float* ln1_b  = (const float*)d_in[3];
  const float* ln2_g  = (const float*)d_in[4];
  const float* ln2_b  = (const float*)d_in[5];
  const float* Wq = (const float*)d_in[6];  const float* bq = (const float*)d_in[7];
  const float* Wk = (const float*)d_in[8];  const float* bk = (const float*)d_in[9];
  const float* Wv = (const float*)d_in[10]; const float* bv = (const float*)d_in[11];
  const float* Wo = (const float*)d_in[12]; const float* bo = (const float*)d_in[13];
  const float* Wg = (const float*)d_in[14]; const float* bg = (const float*)d_in[15];
  const float* W1 = (const float*)d_in[16]; const float* b1 = (const float*)d_in[17];
  const float* W2 = (const float*)d_in[18]; const float* b2 = (const float*)d_in[19];
  const float* ls    = (const float*)d_in[20];
  const float* alpha = (const float*)d_in[21];
  float* out = (float*)d_out;

  // ws layout:
  // [0,128MiB): H bf16 (MLP stage) | BUFA f32 (q_full, first 64MiB) | BUFB f32 (aligned1, @64MiB)
  //             SIM f32 [32768][640] (84MiB at base; live only between simA and attnB,
  //             when BUFA is dead and BUFB not yet written)
  // [128,160MiB): CBF bf16 [32768][512]: XBF -> QBF -> ABF -> YBF (sequential lifetimes)
  // [160MiB...): weight transposes, K/V, pad, per-row stats, KBF
  char* base = (char*)d_ws;
  __hip_bfloat16* H   = (__hip_bfloat16*)base;
  float* BUFA = (float*)base;
  float* SIM  = (float*)base;
  float* BUFB = (float*)(base + ((size_t)64 << 20));
  __hip_bfloat16* CBF = (__hip_bfloat16*)(base + ((size_t)128 << 20));
  char* p = base + ((size_t)160 << 20);
  __hip_bfloat16* WqT = (__hip_bfloat16*)p; p += (size_t)512 * 512 * 2;
  __hip_bfloat16* WoT = (__hip_bfloat16*)p; p += (size_t)512 * 512 * 2;
  __hip_bfloat16* W1T = (__hip_bfloat16*)p; p += (size_t)2048 * 512 * 2;
  __hip_bfloat16* W2T = (__hip_bfloat16*)p; p += (size_t)512 * 2048 * 2;
  float* KF = (float*)p; p += (size_t)BT * CVC * 4;
  float* VF = (float*)p; p += (size_t)BT * CVC * 4;
  int* PADF = (int*)p;  p += 4096;
  float* MEAN1 = (float*)p; p += (size_t)NROW * 4;
  float* RSTD1 = (float*)p; p += (size_t)NROW * 4;
  float* XRMS  = (float*)p; p += (size_t)NROW * 4;
  float* GPRE  = (float*)p; p += (size_t)NROW * 4;
  float* CONF  = (float*)p; p += (size_t)NROW * 4;
  __hip_bfloat16* KBF = (__hip_bfloat16*)p; p += (size_t)64 * 80 * 64 * 2;

  stats1_kernel<<<NROW / 4, 256, 0, stream>>>(visual, ln1_g, ln1_b, Wg, bg,
                                              MEAN1, RSTD1, XRMS, GPRE, CBF);
  convT_kernel<<<dim3(16, 16), dim3(32, 8), 0, stream>>>(Wq, WqT, 512, 512);
  convT_kernel<<<dim3(16, 16), dim3(32, 8), 0, stream>>>(Wo, WoT, 512, 512);
  convT_kernel<<<dim3(64, 16), dim3(32, 8), 0, stream>>>(W1, W1T, 512, 2048);
  convT_kernel<<<dim3(16, 64), dim3(32, 8), 0, stream>>>(W2, W2T, 2048, 512);

  // q_full = x_bf @ Wq + bq  (f32 out for l2norm)
  mfma_gemm<0><<<dim3(2, 128), 512, 0, stream>>>(CBF, WqT, bq, BUFA, nullptr, NROW, 512, 512);
  // q normalized -> bf16 (CBF; XBF dead)
  l2norm_kernel<<<NROW / 4, 256, 0, stream>>>(BUFA, CBF);

  kv2_gemm<<<dim3(8, 20), 256, 0, stream>>>(text, Wk, bk, Wv, bv, KF, VF, BT, CVC, CVC);
  knorm_kernel<<<BT / 4, 256, 0, stream>>>(KF, text, PADF);
  kbf_kernel<<<64, 256, 0, stream>>>(KF, KBF);

  // attention phase A: SIM = q . k (MFMA); BUFA dead after l2norm
  simA_kernel<<<NROW / 64, 256, 0, stream>>>(CBF, KBF, SIM);
  // attention phase B: select/softmax/nucleus/entropy/PV -> ABF (CBF; QBF dead)
  attnB_kernel<<<NROW / 32, 256, 0, stream>>>(SIM, VF, PADF, ls, CONF, CBF);

  // aligned1 = aligned0 @ Wo + bo (SIM dead; BUFB safe to write)
  mfma_gemm<0><<<dim3(2, 128), 512, 0, stream>>>(CBF, WoT, bo, BUFB, nullptr, NROW, 512, 512);

  // y -> out (f32), LN2(y) -> CBF bf16 (ABF dead)
  combine_kernel<<<NROW / 4, 256, 0, stream>>>(BUFB, visual, MEAN1, RSTD1, ln1_g, ln1_b,
                                               XRMS, GPRE, CONF, alpha, ln2_g, ln2_b, out, CBF);

  // h = gelu(LN2(y) @ W1 + b1) -> bf16 H (BUFA/BUFB/SIM dead)
  mfma_gemm<1><<<dim3(8, 128), 512, 0, stream>>>(CBF, W1T, b1, nullptr, H, NROW, 2048, 512);

  // out = y + h @ W2 + b2
  mfma_gemm<2><<<dim3(2, 128), 512, 0, stream>>>(H, W2T, b2, out, nullptr, NROW, 512, 2048);
}

// Round 11
// 520.928 us; speedup vs baseline: 1.0421x; 1.0421x over previous
//
#include <hip/hip_runtime.h>
#include <hip/hip_bf16.h>
#include <math.h>

#define NROW 32768   // B*N
#define CVC  512
#define T77  77
#define BT   616     // B*T
#define HHC  8
#define DHC  64

typedef __attribute__((ext_vector_type(8))) short bf16x8;
typedef __attribute__((ext_vector_type(4))) float f32x4;

__device__ __forceinline__ void gload_lds16(const void* g, void* l) {
  __builtin_amdgcn_global_load_lds(
      (__attribute__((address_space(1))) void*)g,
      (__attribute__((address_space(3))) void*)l, 16, 0, 0);
}

__device__ __forceinline__ float wave_reduce_sum(float v) {
  #pragma unroll
  for (int s = 32; s > 0; s >>= 1) v += __shfl_xor(v, s, 64);
  return v;
}

// Per-row LN1 stats + x_rms + gate pre-act + x in bf16.
// Wave-per-row: 64 lanes x 8 f32 (two float4 loads), shfl-only reductions, no barriers.
__global__ __launch_bounds__(256)
void stats1_kernel(const float* __restrict__ visual, const float* __restrict__ g,
                   const float* __restrict__ b, const float* __restrict__ Wg,
                   const float* __restrict__ bg,
                   float* __restrict__ mean1, float* __restrict__ rstd1,
                   float* __restrict__ xrms, float* __restrict__ gpre,
                   __hip_bfloat16* __restrict__ xbf) {
  const int lane = threadIdx.x & 63;
  const int row  = blockIdx.x * 4 + (threadIdx.x >> 6);
  const float* vr = visual + (size_t)row * CVC + lane * 8;
  float4 va = *(const float4*)vr;
  float4 vb = *(const float4*)(vr + 4);
  float v[8] = {va.x, va.y, va.z, va.w, vb.x, vb.y, vb.z, vb.w};
  float s = 0.f;
  #pragma unroll
  for (int i = 0; i < 8; i++) s += v[i];
  float m = wave_reduce_sum(s) * (1.0f / CVC);
  float s2 = 0.f;
  #pragma unroll
  for (int i = 0; i < 8; i++) { float d = v[i] - m; s2 += d * d; }
  float rs = rsqrtf(wave_reduce_sum(s2) * (1.0f / CVC) + 1e-5f);
  const float4 g0 = *(const float4*)(g + lane * 8), g1v = *(const float4*)(g + lane * 8 + 4);
  const float4 b0 = *(const float4*)(b + lane * 8), b1v = *(const float4*)(b + lane * 8 + 4);
  const float4 w0 = *(const float4*)(Wg + lane * 8), w1 = *(const float4*)(Wg + lane * 8 + 4);
  float gg[8] = {g0.x, g0.y, g0.z, g0.w, g1v.x, g1v.y, g1v.z, g1v.w};
  float bb[8] = {b0.x, b0.y, b0.z, b0.w, b1v.x, b1v.y, b1v.z, b1v.w};
  float ww[8] = {w0.x, w0.y, w0.z, w0.w, w1.x, w1.y, w1.z, w1.w};
  float x[8], sx2 = 0.f, sg = 0.f;
  union { bf16x8 v8; __hip_bfloat16 h[8]; } u;
  #pragma unroll
  for (int i = 0; i < 8; i++) {
    x[i] = (v[i] - m) * rs * gg[i] + bb[i];
    sx2 += x[i] * x[i];
    sg  += x[i] * ww[i];
    u.h[i] = __float2bfloat16(x[i]);
  }
  *(bf16x8*)(xbf + (size_t)row * CVC + lane * 8) = u.v8;
  sx2 = wave_reduce_sum(sx2);
  sg  = wave_reduce_sum(sg);
  if (lane == 0) {
    mean1[row] = m; rstd1[row] = rs;
    xrms[row] = sqrtf(sx2 * (1.0f / CVC)) + 1e-6f;
    gpre[row] = sg + bg[0];
  }
}

// W[K][N] f32 -> Wt[N][K] bf16 (tiled transpose)
__global__ void convT_kernel(const float* __restrict__ W, __hip_bfloat16* __restrict__ Wt,
                             int K, int N) {
  __shared__ float t[32][33];
  int n0 = blockIdx.x * 32, k0 = blockIdx.y * 32;
  int tx = threadIdx.x, ty = threadIdx.y;   // 32, 8
  #pragma unroll
  for (int i = 0; i < 32; i += 8) t[ty + i][tx] = W[(size_t)(k0 + ty + i) * N + n0 + tx];
  __syncthreads();
  #pragma unroll
  for (int i = 0; i < 32; i += 8)
    Wt[(size_t)(n0 + ty + i) * K + k0 + tx] = __float2bfloat16(t[tx][ty + i]);
}

// MFMA bf16 GEMM: C[M,N] = A[M,K] @ Bt[N,K]^T + bias
// 256x256 tile, BK=64, 8 waves (2x4), 4-phase-per-K-tile schedule with counted
// vmcnt (never drains to 0 until the LAST tile), T2 XOR-swizzled LDS (inverse swizzle
// applied to global source; global_load_lds writes linearly), T5 setprio.
// EPI 1: sigmoid-gelu -> bf16 (LDS-coalesced) | 2: out += v (LDS-coalesced f32 RMW)
// EPI 3: bf16 store (LDS-coalesced) + per-row partial sum-of-squares of the exact
//        f32 values -> ps[(bn>>8)*4+wn][row] (8 disjoint partials/row, no atomics).
template<int EPI>
__global__ __launch_bounds__(512, 2)
void mfma_gemm(const __hip_bfloat16* __restrict__ A, const __hip_bfloat16* __restrict__ Bt,
               const float* __restrict__ bias, float* __restrict__ out,
               __hip_bfloat16* __restrict__ outbf, float* __restrict__ ps,
               int M, int N, int K) {
  __shared__ __align__(16) char lds[131072];   // A: 2 x 32KB @0, B: 2 x 32KB @64KB
  const int tid = threadIdx.x;
  const int lane = tid & 63;
  const int wid  = tid >> 6;

  // XCD-aware bijective swizzle (all launches have nwg % 8 == 0)
  const int nwg  = gridDim.x * gridDim.y;
  const int orig = blockIdx.y * gridDim.x + blockIdx.x;
  const int wg   = (orig & 7) * (nwg >> 3) + (orig >> 3);
  const int bx = wg % gridDim.x;
  const int by = wg / gridDim.x;
  const int bm = by * 256, bn = bx * 256;

  const int wm = wid >> 2, wn = wid & 3;       // wave -> 128x64 sub-tile
  const int lrow = lane & 15, kq = lane >> 4;

  f32x4 acc[8][4] = {};

  // ---- staging: per gload, lane covers row r_in (of 8) x swizzled 16B block ----
  const int r_in = lane >> 3;                  // 0..7
  const int cblk = (lane & 7) ^ r_in;          // inverse swizzle on global source
  const __hip_bfloat16* gA = A  + (size_t)(bm + r_in) * K + cblk * 8;
  const __hip_bfloat16* gB = Bt + (size_t)(bn + r_in) * K + cblk * 8;
  char* ldsA = lds;
  char* ldsB = lds + 65536;

  auto stageA = [&](int buf, int k0, int half) {
    #pragma unroll
    for (int j = 0; j < 2; j++) {
      int R0 = half * 128 + wid * 16 + j * 8;
      gload_lds16(gA + (size_t)R0 * K + k0, ldsA + buf * 32768 + R0 * 128);
    }
  };
  auto stageB = [&](int buf, int k0, int half) {
    #pragma unroll
    for (int j = 0; j < 2; j++) {
      int R0 = half * 128 + wid * 16 + j * 8;
      gload_lds16(gB + (size_t)R0 * K + k0, ldsB + buf * 32768 + R0 * 128);
    }
  };

  // ---- swizzled LDS reads: blk = (kk*4+kq) ^ (row&7), row&7 == lrow&7 ----
  const int swz = lrow & 7;
  auto ldA = [&](int buf, int m, int kk) -> bf16x8 {
    int r = wm * 128 + m * 16 + lrow;
    int blk = (kk * 4 + kq) ^ swz;
    return *(const bf16x8*)(ldsA + buf * 32768 + r * 128 + blk * 16);
  };
  auto ldB = [&](int buf, int n, int kk) -> bf16x8 {
    int r = wn * 64 + n * 16 + lrow;
    int blk = (kk * 4 + kq) ^ swz;
    return *(const bf16x8*)(ldsB + buf * 32768 + r * 128 + blk * 16);
  };

  const int NT = K >> 6;
  // prologue issue order must match steady-state: B(0), A(0), B(1)  (12 loads)
  stageB(0, 0, 0); stageB(0, 0, 1);
  stageA(0, 0, 0); stageA(0, 0, 1);
  stageB(1, 64, 0); stageB(1, 64, 1);

  bf16x8 af[4][2], bfv[4][2];
  for (int t = 0; t < NT; ++t) {
    const int cur = t & 1;
    // ---- B1: tile t fully landed. Steady state: allow B(t+1) (4 loads) in flight.
    //      Last tile: nothing newer was staged -> full drain. ----
    if (t < NT - 1) {
      asm volatile("s_waitcnt vmcnt(4)" ::: "memory");
    } else {
      asm volatile("s_waitcnt vmcnt(0)" ::: "memory");
    }
    __builtin_amdgcn_s_barrier();
    asm volatile("" ::: "memory");

    // ph0: read af m0..3 + bf n0..1; stage A(t+1) half0; MFMA quadrant (m0-3, n0-1)
    #pragma unroll
    for (int m = 0; m < 4; m++) { af[m][0] = ldA(cur, m, 0); af[m][1] = ldA(cur, m, 1); }
    #pragma unroll
    for (int n = 0; n < 2; n++) { bfv[n][0] = ldB(cur, n, 0); bfv[n][1] = ldB(cur, n, 1); }
    if (t + 1 < NT) stageA(cur ^ 1, (t + 1) << 6, 0);
    __builtin_amdgcn_s_setprio(1);
    #pragma unroll
    for (int m = 0; m < 4; m++)
      #pragma unroll
      for (int n = 0; n < 2; n++) {
        acc[m][n] = __builtin_amdgcn_mfma_f32_16x16x32_bf16(af[m][0], bfv[n][0], acc[m][n], 0, 0, 0);
        acc[m][n] = __builtin_amdgcn_mfma_f32_16x16x32_bf16(af[m][1], bfv[n][1], acc[m][n], 0, 0, 0);
      }
    __builtin_amdgcn_s_setprio(0);

    // ph1: read bf n2..3; stage A(t+1) half1; MFMA quadrant (m0-3, n2-3)
    #pragma unroll
    for (int n = 2; n < 4; n++) { bfv[n][0] = ldB(cur, n, 0); bfv[n][1] = ldB(cur, n, 1); }
    if (t + 1 < NT) stageA(cur ^ 1, (t + 1) << 6, 1);
    __builtin_amdgcn_s_setprio(1);
    #pragma unroll
    for (int m = 0; m < 4; m++)
      #pragma unroll
      for (int n = 2; n < 4; n++) {
        acc[m][n] = __builtin_amdgcn_mfma_f32_16x16x32_bf16(af[m][0], bfv[n][0], acc[m][n], 0, 0, 0);
        acc[m][n] = __builtin_amdgcn_mfma_f32_16x16x32_bf16(af[m][1], bfv[n][1], acc[m][n], 0, 0, 0);
      }
    __builtin_amdgcn_s_setprio(0);

    // ---- B2: all waves' B-slot reads COMPLETE (lgkm drained) before restage ----
    asm volatile("s_waitcnt lgkmcnt(0)" ::: "memory");
    __builtin_amdgcn_s_barrier();
    asm volatile("" ::: "memory");

    // ph2: read af m4..7; stage B(t+2) half0 into cur buf; MFMA (m4-7, n0-1)
    #pragma unroll
    for (int m = 0; m < 4; m++) { af[m][0] = ldA(cur, m + 4, 0); af[m][1] = ldA(cur, m + 4, 1); }
    if (t + 2 < NT) stageB(cur, (t + 2) << 6, 0);
    __builtin_amdgcn_s_setprio(1);
    #pragma unroll
    for (int m = 0; m < 4; m++)
      #pragma unroll
      for (int n = 0; n < 2; n++) {
        acc[m + 4][n] = __builtin_amdgcn_mfma_f32_16x16x32_bf16(af[m][0], bfv[n][0], acc[m + 4][n], 0, 0, 0);
        acc[m + 4][n] = __builtin_amdgcn_mfma_f32_16x16x32_bf16(af[m][1], bfv[n][1], acc[m + 4][n], 0, 0, 0);
      }
    __builtin_amdgcn_s_setprio(0);

    // ph3: stage B(t+2) half1; MFMA (m4-7, n2-3)
    if (t + 2 < NT) stageB(cur, (t + 2) << 6, 1);
    __builtin_amdgcn_s_setprio(1);
    #pragma unroll
    for (int m = 0; m < 4; m++)
      #pragma unroll
      for (int n = 2; n < 4; n++) {
        acc[m + 4][n] = __builtin_amdgcn_mfma_f32_16x16x32_bf16(af[m][0], bfv[n][0], acc[m + 4][n], 0, 0, 0);
        acc[m + 4][n] = __builtin_amdgcn_mfma_f32_16x16x32_bf16(af[m][1], bfv[n][1], acc[m + 4][n], 0, 0, 0);
      }
    __builtin_amdgcn_s_setprio(0);
    // no barrier here: next iteration opens with vmcnt+barrier (B1)
  }

  // epilogue: fragment row = kq*4 + rg, col = lrow
  const int c0 = bn + wn * 64 + lrow;
  if (EPI == 1) {
    // bf16 output via per-wave 16KB LDS (kq-swizzled, conflict-free), 16B/lane stores.
    // gelu: sigmoid form, max |err vs exact| ~5e-4 << bf16 quantization of H.
    __syncthreads();                    // K-loop LDS fully dead
    char* eb = lds + wid * 16384;       // 128 rows x 128B
    #pragma unroll
    for (int n = 0; n < 4; n++) {
      float bval = bias[c0 + n * 16];
      #pragma unroll
      for (int m = 0; m < 8; m++) {
        #pragma unroll
        for (int rg = 0; rg < 4; rg++) {
          int lr  = m * 16 + kq * 4 + rg;               // (lr>>2)&3 == kq
          int lcb = (n * 32 + lrow * 2) ^ (kq << 5);    // swizzled byte-in-row
          float v = acc[m][n][rg] + bval;
          float ge = v / (1.0f + __expf(v * (-1.5957691216f - 0.0713548162f * v * v)));
          *(__hip_bfloat16*)(eb + lr * 128 + lcb) = __float2bfloat16(ge);
        }
      }
    }
    asm volatile("s_waitcnt lgkmcnt(0)" ::: "memory");  // wave-local LDS drain
    __builtin_amdgcn_sched_barrier(0);
    const int rr = lane >> 3, bb = lane & 7;
    #pragma unroll
    for (int it = 0; it < 16; it++) {
      int lr  = it * 8 + rr;
      int lcb = (bb << 4) ^ (((lr >> 2) & 3) << 5);
      uint4 v = *(const uint4*)(eb + lr * 128 + lcb);
      size_t go = (size_t)(bm + wm * 128 + lr) * N + (bn + wn * 64 + bb * 8);
      *(uint4*)(&outbf[go]) = v;
    }
  } else if (EPI == 3) {
    // bf16 output + exact-f32 per-row partial sum of squares.
    __syncthreads();                    // K-loop LDS fully dead
    char* eb = lds + wid * 16384;       // 128 rows x 128B
    float bv4[4];
    #pragma unroll
    for (int n = 0; n < 4; n++) bv4[n] = bias[c0 + n * 16];
    const int psi = (bn >> 8) * 4 + wn; // 8 disjoint partials per row (N=512 only)
    #pragma unroll
    for (int m = 0; m < 8; m++) {
      #pragma unroll
      for (int rg = 0; rg < 4; rg++) {
        int lr = m * 16 + kq * 4 + rg;
        float ss = 0.f;
        #pragma unroll
        for (int n = 0; n < 4; n++) {
          float v = acc[m][n][rg] + bv4[n];
          ss += v * v;
          int lcb = (n * 32 + lrow * 2) ^ (kq << 5);
          *(__hip_bfloat16*)(eb + lr * 128 + lcb) = __float2bfloat16(v);
        }
        // reduce over the 16-lane lrow group (lanes kq*16..kq*16+15)
        ss += __shfl_xor(ss, 1, 64); ss += __shfl_xor(ss, 2, 64);
        ss += __shfl_xor(ss, 4, 64); ss += __shfl_xor(ss, 8, 64);
        if (lrow == 0) ps[(size_t)psi * M + (bm + wm * 128 + lr)] = ss;
      }
    }
    asm volatile("s_waitcnt lgkmcnt(0)" ::: "memory");
    __builtin_amdgcn_sched_barrier(0);
    const int rr = lane >> 3, bb = lane & 7;
    #pragma unroll
    for (int it = 0; it < 16; it++) {
      int lr  = it * 8 + rr;
      int lcb = (bb << 4) ^ (((lr >> 2) & 3) << 5);
      uint4 v = *(const uint4*)(eb + lr * 128 + lcb);
      size_t go = (size_t)(bm + wm * 128 + lr) * N + (bn + wn * 64 + bb * 8);
      *(uint4*)(&outbf[go]) = v;
    }
  } else {
    // f32 output via per-wave 16KB LDS, two 64-row half-passes (f32 tile = 32KB).
    __syncthreads();                    // K-loop LDS fully dead
    char* eb = lds + wid * 16384;       // 64 rows x 256B
    const int rr = lane >> 4, bb = lane & 15;
    #pragma unroll
    for (int half = 0; half < 2; half++) {
      if (half) {                        // half0 reads done before overwrite
        asm volatile("s_waitcnt lgkmcnt(0)" ::: "memory");
        __builtin_amdgcn_sched_barrier(0);
      }
      #pragma unroll
      for (int n = 0; n < 4; n++) {
        float bval = bias[c0 + n * 16];
        #pragma unroll
        for (int m = 0; m < 4; m++) {
          #pragma unroll
          for (int rg = 0; rg < 4; rg++) {
            int lr  = m * 16 + kq * 4 + rg;             // 0..63
            int byo = (n * 64 + lrow * 4) ^ (kq << 6);  // swizzled byte-in-row
            *(float*)(eb + lr * 256 + byo) = acc[half * 4 + m][n][rg] + bval;
          }
        }
      }
      asm volatile("s_waitcnt lgkmcnt(0)" ::: "memory");
      __builtin_amdgcn_sched_barrier(0);
      #pragma unroll
      for (int it = 0; it < 16; it++) {
        int lr  = it * 4 + rr;
        int byo = (bb * 16) ^ (((lr >> 2) & 3) << 6);
        float4 v4 = *(const float4*)(eb + lr * 256 + byo);
        size_t go = (size_t)(bm + wm * 128 + half * 64 + lr) * N + (bn + wn * 64 + bb * 4);
        if (EPI == 0) {
          *(float4*)(&out[go]) = v4;
        } else {
          const float4 o = *(const float4*)(&out[go]);
          v4.x += o.x; v4.y += o.y; v4.z += o.z; v4.w += o.w;
          *(float4*)(&out[go]) = v4;
        }
      }
    }
  }
}

// Fused K/V projection GEMM (one launch, 160 blocks): by<10 -> K, else V
__global__ void kv2_gemm(const float* __restrict__ A,
                         const float* __restrict__ Wk, const float* __restrict__ bk,
                         const float* __restrict__ Wv, const float* __restrict__ bv,
                         float* __restrict__ KF, float* __restrict__ VF,
                         int M, int K, int N) {
  __shared__ float As[16][68];
  __shared__ float Bs[16][68];
  const bool isV = blockIdx.y >= 10;
  const float* W    = isV ? Wv : Wk;
  const float* bias = isV ? bv : bk;
  float* out        = isV ? VF : KF;
  int tid = threadIdx.x;
  int bm = (isV ? blockIdx.y - 10 : blockIdx.y) * 64, bn = blockIdx.x * 64;
  int ty = tid >> 4, tx = tid & 15;
  float acc[4][4] = {};
  for (int k0 = 0; k0 < K; k0 += 16) {
    #pragma unroll
    for (int i = 0; i < 4; i++) {
      int idx = tid + i * 256;
      int mm = idx >> 4, kk = idx & 15;
      int row = bm + mm;
      As[kk][mm] = (row < M) ? A[(size_t)row * K + k0 + kk] : 0.f;
    }
    #pragma unroll
    for (int i = 0; i < 4; i++) {
      int idx = tid + i * 256;
      int kk = idx >> 6, nn = idx & 63;
      Bs[kk][nn] = W[(size_t)(k0 + kk) * N + bn + nn];
    }
    __syncthreads();
    #pragma unroll
    for (int kk = 0; kk < 16; kk++) {
      float4 av = *(const float4*)&As[kk][ty * 4];
      float4 bv4 = *(const float4*)&Bs[kk][tx * 4];
      float a_[4] = {av.x, av.y, av.z, av.w};
      float b_[4] = {bv4.x, bv4.y, bv4.z, bv4.w};
      #pragma unroll
      for (int i = 0; i < 4; i++)
        #pragma unroll
        for (int j = 0; j < 4; j++)
          acc[i][j] = fmaf(a_[i], b_[j], acc[i][j]);
    }
    __syncthreads();
  }
  #pragma unroll
  for (int i = 0; i < 4; i++) {
    int row = bm + ty * 4 + i;
    if (row >= M) continue;
    #pragma unroll
    for (int j = 0; j < 4; j++) {
      int col = bn + tx * 4 + j;
      out[(size_t)row * N + col] = acc[i][j] + bias[col];
    }
  }
}

// L2 normalize: read bf16 q_full + 8 exact-f32 partial sumsq -> bf16 normalized.
__global__ __launch_bounds__(256)
void l2norm_kernel(const __hip_bfloat16* __restrict__ qf, const float* __restrict__ ps,
                   __hip_bfloat16* __restrict__ qbf) {
  const int lane = threadIdx.x & 63;
  const int row  = blockIdx.x * 4 + (threadIdx.x >> 6);
  float s = 0.f;
  #pragma unroll
  for (int j = 0; j < 8; j++) s += ps[(size_t)j * NROW + row];
  float inv = 1.0f / fmaxf(sqrtf(s), 1e-6f);
  union { bf16x8 v8; __hip_bfloat16 h[8]; } u;
  u.v8 = *(const bf16x8*)(qf + (size_t)row * CVC + lane * 8);
  #pragma unroll
  for (int i = 0; i < 8; i++)
    u.h[i] = __float2bfloat16(__bfloat162float(u.h[i]) * inv);
  *(bf16x8*)(qbf + (size_t)row * CVC + lane * 8) = u.v8;
}

// Wave-per-row K-norm + pad detection (616 rows = 154 blocks x 4 waves)
__global__ __launch_bounds__(256)
void knorm_kernel(float* __restrict__ kf, const float* __restrict__ text,
                  int* __restrict__ pad) {
  const int lane = threadIdx.x & 63;
  const int row  = blockIdx.x * 4 + (threadIdx.x >> 6);
  float* p = kf + (size_t)row * CVC + lane * 8;
  const float* tx = text + (size_t)row * CVC + lane * 8;
  float4 va = *(const float4*)p;
  float4 vb = *(const float4*)(p + 4);
  float4 ta = *(const float4*)tx;
  float4 tb = *(const float4*)(tx + 4);
  float v[8] = {va.x, va.y, va.z, va.w, vb.x, vb.y, vb.z, vb.w};
  float t[8] = {ta.x, ta.y, ta.z, ta.w, tb.x, tb.y, tb.z, tb.w};
  float s = 0.f, a = 0.f;
  #pragma unroll
  for (int i = 0; i < 8; i++) { s += v[i] * v[i]; a += fabsf(t[i]); }
  s = wave_reduce_sum(s);
  a = wave_reduce_sum(a);
  float inv = 1.0f / fmaxf(sqrtf(s), 1e-6f);
  float4 o0 = {v[0] * inv, v[1] * inv, v[2] * inv, v[3] * inv};
  float4 o1 = {v[4] * inv, v[5] * inv, v[6] * inv, v[7] * inv};
  *(float4*)p = o0;
  *(float4*)(p + 4) = o1;
  if (lane == 0) pad[row] = (a <= 1e-6f) ? 1 : 0;
}

// Repack normalized K into per-(b,h) MFMA B^T tiles: KBF[b][h][80][64] bf16, t>=77 zero
__global__ void kbf_kernel(const float* __restrict__ kf, __hip_bfloat16* __restrict__ kbf) {
  int bh = blockIdx.x;                 // 64 blocks
  int b = bh >> 3, h = bh & 7;
  int tid = threadIdx.x;
  for (int i = tid; i < 80 * 64; i += 256) {
    int t = i >> 6, d = i & 63;
    float v = (t < T77) ? kf[(size_t)(b * T77 + t) * CVC + h * DHC + d] : 0.0f;
    kbf[(size_t)bh * (80 * 64) + i] = __float2bfloat16(v);
  }
}

// Attention phase A: SIM[row][h][t] = q_row_h . k_t_h via MFMA (raw dot, no scale)
__global__ __launch_bounds__(256)
void simA_kernel(const __hip_bfloat16* __restrict__ qbf, const __hip_bfloat16* __restrict__ kbf,
                 float* __restrict__ sim) {
  const int tid = threadIdx.x;
  const int wid = tid >> 6, lane = tid & 63;
  const int r0 = blockIdx.x * 64 + wid * 16;     // 16 rows per wave
  const int b = (blockIdx.x * 64) >> 12;         // 4096 rows per batch
  const int lrow = lane & 15, kq = lane >> 4;
  const __hip_bfloat16* qrow = qbf + (size_t)(r0 + lrow) * CVC;
  for (int h = 0; h < HHC; h++) {
    const __hip_bfloat16* kb = kbf + (size_t)(b * 8 + h) * (80 * 64);
    f32x4 acc[5] = {};
    #pragma unroll
    for (int ks = 0; ks < 2; ks++) {
      bf16x8 af = *(const bf16x8*)(qrow + h * DHC + ks * 32 + kq * 8);
      #pragma unroll
      for (int n = 0; n < 5; n++) {
        bf16x8 bf = *(const bf16x8*)(kb + (size_t)(n * 16 + lrow) * DHC + ks * 32 + kq * 8);
        acc[n] = __builtin_amdgcn_mfma_f32_16x16x32_bf16(af, bf, acc[n], 0, 0, 0);
      }
    }
    // C layout: row = r0 + kq*4 + reg, col = n*16 + lrow
    #pragma unroll
    for (int n = 0; n < 5; n++)
      #pragma unroll
      for (int rg = 0; rg < 4; rg++)
        sim[(size_t)(r0 + kq * 4 + rg) * 640 + h * 80 + n * 16 + lrow] = acc[n][rg];
  }
}

// Attention phase B: per (row,head) thread streams its 80-entry sim row (coalesced),
// top-5 / softmax / nucleus / entropy / conf, then cooperative sparse PV -> bf16.
__global__ __launch_bounds__(256)
void attnB_kernel(const float* __restrict__ sim, const float* __restrict__ vf,
                  const int* __restrict__ pad, const float* __restrict__ ls,
                  float* __restrict__ conf_out, __hip_bfloat16* __restrict__ abf) {
  __shared__ float spr[32][HHC][5];
  __shared__ int   sti[32][HHC][5];
  __shared__ float sconf[256];
  __shared__ float sbias[80];
  const int tid = threadIdx.x;
  const int r = tid >> 3, h = tid & 7;
  const int r0 = blockIdx.x * 32;
  const int b = r0 >> 12;
  const float lsv = fminf(fmaxf(ls[0], -2.0f), 2.0f);
  const float scale = expf(lsv) * 0.125f;   // / sqrt(64)

  if (tid < 80) sbias[tid] = (tid < T77 && !pad[b * T77 + tid]) ? 0.0f : -INFINITY;
  __syncthreads();

  // stream 80 sim values (20 float4, contiguous per thread, coalesced per block)
  float t0 = -INFINITY, t1 = -INFINITY, t2 = -INFINITY, t3 = -INFINITY, t4 = -INFINITY;
  int   i0 = -1, i1 = -1, i2 = -1, i3 = -1, i4 = -1;
  const float4* simp = (const float4*)(sim + (size_t)(r0 + r) * 640 + h * 80);
  #pragma unroll
  for (int tt = 0; tt < 20; tt++) {
    float4 v4 = simp[tt];
    #pragma unroll
    for (int j = 0; j < 4; j++) {
      int t = tt * 4 + j;
      float sv = (j == 0 ? v4.x : j == 1 ? v4.y : j == 2 ? v4.z : v4.w);
      float s = sv * scale + sbias[t];
      if (s > t4) {
        t4 = s; i4 = t;
        if (t4 > t3) { float f = t3; t3 = t4; t4 = f; int x = i3; i3 = i4; i4 = x; }
        if (t3 > t2) { float f = t2; t2 = t3; t3 = f; int x = i2; i2 = i3; i3 = x; }
        if (t2 > t1) { float f = t1; t1 = t2; t2 = f; int x = i1; i1 = i2; i2 = x; }
        if (t1 > t0) { float f = t0; t0 = t1; t1 = f; int x = i0; i0 = i1; i1 = x; }
      }
    }
  }

  // softmax over top-5
  float e0 = (t0 == -INFINITY) ? 0.f : expf(t0 - t0);
  float e1 = (t1 == -INFINITY) ? 0.f : expf(t1 - t0);
  float e2 = (t2 == -INFINITY) ? 0.f : expf(t2 - t0);
  float e3 = (t3 == -INFINITY) ? 0.f : expf(t3 - t0);
  float e4 = (t4 == -INFINITY) ? 0.f : expf(t4 - t0);
  float invs = 1.0f / (e0 + e1 + e2 + e3 + e4);
  float p0 = e0 * invs, p1 = e1 * invs, p2 = e2 * invs, p3 = e3 * invs, p4 = e4 * invs;
  // nucleus: inclusive cumsum <= 0.9, top-1 forced
  float c1 = p0 + p1, c2 = c1 + p2, c3 = c2 + p3, c4 = c3 + p4;
  bool k1 = (c1 <= 0.9f), k2 = (c2 <= 0.9f), k3 = (c3 <= 0.9f), k4 = (c4 <= 0.9f);
  float skeep = p0 + (k1 ? p1 : 0.f) + (k2 ? p2 : 0.f) + (k3 ? p3 : 0.f) + (k4 ? p4 : 0.f);
  float rn = 1.0f / fmaxf(skeep, 1e-6f);
  float w0 = p0 * rn, w1 = k1 ? p1 * rn : 0.f, w2 = k2 ? p2 * rn : 0.f,
        w3 = k3 ? p3 * rn : 0.f, w4 = k4 ? p4 * rn : 0.f;
  int nnz = (w0 > 0.f) + (w1 > 0.f) + (w2 > 0.f) + (w3 > 0.f) + (w4 > 0.f);
  float ent = 0.f;
  {
    float pc;
    pc = fmaxf(w0, 1e-8f); ent -= pc * logf(pc);
    pc = fmaxf(w1, 1e-8f); ent -= pc * logf(pc);
    pc = fmaxf(w2, 1e-8f); ent -= pc * logf(pc);
    pc = fmaxf(w3, 1e-8f); ent -= pc * logf(pc);
    pc = fmaxf(w4, 1e-8f); ent -= pc * logf(pc);
  }
  ent += (float)(T77 - 5) * 1.8420681e-7f;   // 72 zero entries at pc=1e-8
  float denom = logf(fmaxf(fmaxf((float)nnz, 1.0f), 2.0f));
  ent /= denom;
  float confh = fminf(fmaxf(w0 * (1.0f - ent), 0.f), 1.f);

  spr[r][h][0] = w0; spr[r][h][1] = w1; spr[r][h][2] = w2; spr[r][h][3] = w3; spr[r][h][4] = w4;
  sti[r][h][0] = i0; sti[r][h][1] = i1; sti[r][h][2] = i2; sti[r][h][3] = i3; sti[r][h][4] = i4;
  sconf[tid] = confh;
  __syncthreads();

  if (tid < 32) {
    float s = 0.f;
    #pragma unroll
    for (int j = 0; j < 8; j++) s += sconf[tid * 8 + j];
    conf_out[r0 + tid] = s * 0.125f;
  }

  // cooperative sparse PV: wave-uniform (row,head) -> coalesced v loads
  #pragma unroll
  for (int it = 0; it < 64; it++) {
    int idx = tid + it * 256;
    int rr = idx >> 9, c = idx & 511, hh = c >> 6;
    float a = 0.f;
    #pragma unroll
    for (int i = 0; i < 5; i++) {
      float pr = spr[rr][hh][i]; int t = sti[rr][hh][i];
      if (pr > 0.f && t >= 0) a = fmaf(pr, vf[((size_t)(b * T77 + t)) * CVC + c], a);
    }
    abf[(size_t)(r0 + rr) * CVC + c] = __float2bfloat16(a);
  }
}

// Trust region + gate + residual -> y (f32 out) AND LN2(y) in bf16.
// aligned read as bf16 + exact-f32 sumsq partials (a_norm exact); wave-per-row.
__global__ __launch_bounds__(256)
void combine_kernel(const __hip_bfloat16* __restrict__ alnbf, const float* __restrict__ ps,
                    const float* __restrict__ visual,
                    const float* __restrict__ m1, const float* __restrict__ r1,
                    const float* __restrict__ g1, const float* __restrict__ b1v,
                    const float* __restrict__ xrms, const float* __restrict__ gpre,
                    const float* __restrict__ conf, const float* __restrict__ alpha,
                    const float* __restrict__ g2, const float* __restrict__ b2v,
                    float* __restrict__ dout, __hip_bfloat16* __restrict__ ybf) {
  const int lane = threadIdx.x & 63;
  const int row  = blockIdx.x * 4 + (threadIdx.x >> 6);
  float s2 = 0.f;
  #pragma unroll
  for (int j = 0; j < 8; j++) s2 += ps[(size_t)j * NROW + row];
  float an = sqrtf(s2);
  float factor = fminf(0.5f * xrms[row] / fmaxf(an, 1e-6f), 1.0f);
  float gate = conf[row] / (1.0f + expf(-gpre[row]));
  float coef = alpha[0] * gate * factor;
  float mm = m1[row], rs = r1[row];
  union { bf16x8 v8; __hip_bfloat16 h[8]; } ua;
  ua.v8 = *(const bf16x8*)(alnbf + (size_t)row * CVC + lane * 8);
  float av[8];
  #pragma unroll
  for (int i = 0; i < 8; i++) av[i] = __bfloat162float(ua.h[i]);
  const float* vr = visual + (size_t)row * CVC + lane * 8;
  float4 va = *(const float4*)vr;
  float4 vb = *(const float4*)(vr + 4);
  float v[8] = {va.x, va.y, va.z, va.w, vb.x, vb.y, vb.z, vb.w};
  const float4 ga = *(const float4*)(g1 + lane * 8), gb = *(const float4*)(g1 + lane * 8 + 4);
  const float4 ba = *(const float4*)(b1v + lane * 8), bb2 = *(const float4*)(b1v + lane * 8 + 4);
  float gg[8] = {ga.x, ga.y, ga.z, ga.w, gb.x, gb.y, gb.z, gb.w};
  float bbv[8] = {ba.x, ba.y, ba.z, ba.w, bb2.x, bb2.y, bb2.z, bb2.w};
  float y[8], sy = 0.f;
  #pragma unroll
  for (int i = 0; i < 8; i++) {
    float x = (v[i] - mm) * rs * gg[i] + bbv[i];
    y[i] = x + coef * av[i];
    sy += y[i];
  }
  float* orow = dout + (size_t)row * CVC + lane * 8;
  float4 o0 = {y[0], y[1], y[2], y[3]};
  float4 o1 = {y[4], y[5], y[6], y[7]};
  *(float4*)orow = o0;
  *(float4*)(orow + 4) = o1;
  float ym = wave_reduce_sum(sy) * (1.0f / CVC);
  float var = 0.f;
  #pragma unroll
  for (int i = 0; i < 8; i++) { float d = y[i] - ym; var += d * d; }
  var = wave_reduce_sum(var) * (1.0f / CVC);
  float rs2 = rsqrtf(var + 1e-5f);
  const float4 g2a = *(const float4*)(g2 + lane * 8), g2b = *(const float4*)(g2 + lane * 8 + 4);
  const float4 b2a = *(const float4*)(b2v + lane * 8), b2b = *(const float4*)(b2v + lane * 8 + 4);
  float g2v[8] = {g2a.x, g2a.y, g2a.z, g2a.w, g2b.x, g2b.y, g2b.z, g2b.w};
  float b2vv[8] = {b2a.x, b2a.y, b2a.z, b2a.w, b2b.x, b2b.y, b2b.z, b2b.w};
  union { bf16x8 v8; __hip_bfloat16 h[8]; } u;
  #pragma unroll
  for (int i = 0; i < 8; i++)
    u.h[i] = __float2bfloat16((y[i] - ym) * rs2 * g2v[i] + b2vv[i]);
  *(bf16x8*)(ybf + (size_t)row * CVC + lane * 8) = u.v8;
}

extern "C" void kernel_launch(void* const* d_in, const int* in_sizes, int n_in,
                              void* d_out, int out_size, void* d_ws, size_t ws_size,
                              hipStream_t stream) {
  const float* visual = (const float*)d_in[0];
  const float* text   = (const float*)d_in[1];
  const float* ln1_g  = (const float*)d_in[2];
  const float* ln1_b  = (const float*)d_in[3];
  const float* ln2_g  = (const float*)d_in[4];
  const float* ln2_b  = (const float*)d_in[5];
  const float* Wq = (const float*)d_in[6];  const float* bq = (const float*)d_in[7];
  const float* Wk = (const float*)d_in[8];  const float* bk = (const float*)d_in[9];
  const float* Wv = (const float*)d_in[10]; const float* bv = (const float*)d_in[11];
  const float* Wo = (const float*)d_in[12]; const float* bo = (const float*)d_in[13];
  const float* Wg = (const float*)d_in[14]; const float* bg = (const float*)d_in[15];
  const float* W1 = (const float*)d_in[16]; const float* b1 = (const float*)d_in[17];
  const float* W2 = (const float*)d_in[18]; const float* b2 = (const float*)d_in[19];
  const float* ls    = (const float*)d_in[20];
  const float* alpha = (const float*)d_in[21];
  float* out = (float*)d_out;

  // ws layout:
  // [0,128MiB): base region, sequential lifetimes:
  //   QBF2 bf16 (Wq out, 32MB) -> SIM f32 [32768][640] (84MB) -> ALNBF bf16 (Wo out,
  //   32MB) -> H bf16 (MLP stage, 128MB)
  // [128,160MiB): CBF bf16 [32768][512]: XBF -> QBF -> ABF -> YBF (sequential)
  // [160MiB...): weight transposes, K/V, pad, per-row stats, KBF, PS partials
  char* base = (char*)d_ws;
  __hip_bfloat16* H     = (__hip_bfloat16*)base;
  __hip_bfloat16* QBF2  = (__hip_bfloat16*)base;
  __hip_bfloat16* ALNBF = (__hip_bfloat16*)base;
  float* SIM  = (float*)base;
  __hip_bfloat16* CBF = (__hip_bfloat16*)(base + ((size_t)128 << 20));
  char* p = base + ((size_t)160 << 20);
  __hip_bfloat16* WqT = (__hip_bfloat16*)p; p += (size_t)512 * 512 * 2;
  __hip_bfloat16* WoT = (__hip_bfloat16*)p; p += (size_t)512 * 512 * 2;
  __hip_bfloat16* W1T = (__hip_bfloat16*)p; p += (size_t)2048 * 512 * 2;
  __hip_bfloat16* W2T = (__hip_bfloat16*)p; p += (size_t)512 * 2048 * 2;
  float* KF = (float*)p; p += (size_t)BT * CVC * 4;
  float* VF = (float*)p; p += (size_t)BT * CVC * 4;
  int* PADF = (int*)p;  p += 4096;
  float* MEAN1 = (float*)p; p += (size_t)NROW * 4;
  float* RSTD1 = (float*)p; p += (size_t)NROW * 4;
  float* XRMS  = (float*)p; p += (size_t)NROW * 4;
  float* GPRE  = (float*)p; p += (size_t)NROW * 4;
  float* CONF  = (float*)p; p += (size_t)NROW * 4;
  __hip_bfloat16* KBF = (__hip_bfloat16*)p; p += (size_t)64 * 80 * 64 * 2;
  float* PS = (float*)p; p += (size_t)8 * NROW * 4;   // shared by Wq->l2norm, Wo->combine

  stats1_kernel<<<NROW / 4, 256, 0, stream>>>(visual, ln1_g, ln1_b, Wg, bg,
                                              MEAN1, RSTD1, XRMS, GPRE, CBF);
  convT_kernel<<<dim3(16, 16), dim3(32, 8), 0, stream>>>(Wq, WqT, 512, 512);
  convT_kernel<<<dim3(16, 16), dim3(32, 8), 0, stream>>>(Wo, WoT, 512, 512);
  convT_kernel<<<dim3(64, 16), dim3(32, 8), 0, stream>>>(W1, W1T, 512, 2048);
  convT_kernel<<<dim3(16, 64), dim3(32, 8), 0, stream>>>(W2, W2T, 2048, 512);

  // q_full = x_bf @ Wq + bq  (bf16 out + exact-f32 row sumsq partials)
  mfma_gemm<3><<<dim3(2, 128), 512, 0, stream>>>(CBF, WqT, bq, nullptr, QBF2, PS,
                                                 NROW, 512, 512);
  // q normalized -> bf16 (CBF; XBF dead)
  l2norm_kernel<<<NROW / 4, 256, 0, stream>>>(QBF2, PS, CBF);

  kv2_gemm<<<dim3(8, 20), 256, 0, stream>>>(text, Wk, bk, Wv, bv, KF, VF, BT, CVC, CVC);
  knorm_kernel<<<BT / 4, 256, 0, stream>>>(KF, text, PADF);
  kbf_kernel<<<64, 256, 0, stream>>>(KF, KBF);

  // attention phase A: SIM = q . k (MFMA); QBF2 dead after l2norm
  simA_kernel<<<NROW / 64, 256, 0, stream>>>(CBF, KBF, SIM);
  // attention phase B: select/softmax/nucleus/entropy/PV -> ABF (CBF; QBF dead)
  attnB_kernel<<<NROW / 32, 256, 0, stream>>>(SIM, VF, PADF, ls, CONF, CBF);

  // aligned1 = aligned0 @ Wo + bo (SIM dead; bf16 out + exact sumsq partials)
  mfma_gemm<3><<<dim3(2, 128), 512, 0, stream>>>(CBF, WoT, bo, nullptr, ALNBF, PS,
                                                 NROW, 512, 512);

  // y -> out (f32), LN2(y) -> CBF bf16 (ABF dead)
  combine_kernel<<<NROW / 4, 256, 0, stream>>>(ALNBF, PS, visual, MEAN1, RSTD1, ln1_g, ln1_b,
                                               XRMS, GPRE, CONF, alpha, ln2_g, ln2_b, out, CBF);

  // h = gelu(LN2(y) @ W1 + b1) -> bf16 H (ALNBF dead)
  mfma_gemm<1><<<dim3(8, 128), 512, 0, stream>>>(CBF, W1T, b1, nullptr, H, nullptr,
                                                 NROW, 2048, 512);

  // out = y + h @ W2 + b2
  mfma_gemm<2><<<dim3(2, 128), 512, 0, stream>>>(H, W2T, b2, out, nullptr, nullptr,
                                                 NROW, 512, 2048);
}

// Round 12
// 500.228 us; speedup vs baseline: 1.0853x; 1.0414x over previous
//
#include <hip/hip_runtime.h>
#include <hip/hip_bf16.h>
#include <math.h>

#define NROW 32768   // B*N
#define CVC  512
#define T77  77
#define BT   616     // B*T
#define HHC  8
#define DHC  64

typedef __attribute__((ext_vector_type(8))) short bf16x8;
typedef __attribute__((ext_vector_type(4))) float f32x4;

__device__ __forceinline__ void gload_lds16(const void* g, void* l) {
  __builtin_amdgcn_global_load_lds(
      (__attribute__((address_space(1))) void*)g,
      (__attribute__((address_space(3))) void*)l, 16, 0, 0);
}

__device__ __forceinline__ float wave_reduce_sum(float v) {
  #pragma unroll
  for (int s = 32; s > 0; s >>= 1) v += __shfl_xor(v, s, 64);
  return v;
}

// Per-row LN1 stats + x_rms + gate pre-act + x in bf16.
// Wave-per-row: 64 lanes x 8 f32 (two float4 loads), shfl-only reductions, no barriers.
__global__ __launch_bounds__(256)
void stats1_kernel(const float* __restrict__ visual, const float* __restrict__ g,
                   const float* __restrict__ b, const float* __restrict__ Wg,
                   const float* __restrict__ bg,
                   float* __restrict__ mean1, float* __restrict__ rstd1,
                   float* __restrict__ xrms, float* __restrict__ gpre,
                   __hip_bfloat16* __restrict__ xbf) {
  const int lane = threadIdx.x & 63;
  const int row  = blockIdx.x * 4 + (threadIdx.x >> 6);
  const float* vr = visual + (size_t)row * CVC + lane * 8;
  float4 va = *(const float4*)vr;
  float4 vb = *(const float4*)(vr + 4);
  float v[8] = {va.x, va.y, va.z, va.w, vb.x, vb.y, vb.z, vb.w};
  float s = 0.f;
  #pragma unroll
  for (int i = 0; i < 8; i++) s += v[i];
  float m = wave_reduce_sum(s) * (1.0f / CVC);
  float s2 = 0.f;
  #pragma unroll
  for (int i = 0; i < 8; i++) { float d = v[i] - m; s2 += d * d; }
  float rs = rsqrtf(wave_reduce_sum(s2) * (1.0f / CVC) + 1e-5f);
  const float4 g0 = *(const float4*)(g + lane * 8), g1v = *(const float4*)(g + lane * 8 + 4);
  const float4 b0 = *(const float4*)(b + lane * 8), b1v = *(const float4*)(b + lane * 8 + 4);
  const float4 w0 = *(const float4*)(Wg + lane * 8), w1 = *(const float4*)(Wg + lane * 8 + 4);
  float gg[8] = {g0.x, g0.y, g0.z, g0.w, g1v.x, g1v.y, g1v.z, g1v.w};
  float bb[8] = {b0.x, b0.y, b0.z, b0.w, b1v.x, b1v.y, b1v.z, b1v.w};
  float ww[8] = {w0.x, w0.y, w0.z, w0.w, w1.x, w1.y, w1.z, w1.w};
  float x[8], sx2 = 0.f, sg = 0.f;
  union { bf16x8 v8; __hip_bfloat16 h[8]; } u;
  #pragma unroll
  for (int i = 0; i < 8; i++) {
    x[i] = (v[i] - m) * rs * gg[i] + bb[i];
    sx2 += x[i] * x[i];
    sg  += x[i] * ww[i];
    u.h[i] = __float2bfloat16(x[i]);
  }
  *(bf16x8*)(xbf + (size_t)row * CVC + lane * 8) = u.v8;
  sx2 = wave_reduce_sum(sx2);
  sg  = wave_reduce_sum(sg);
  if (lane == 0) {
    mean1[row] = m; rstd1[row] = rs;
    xrms[row] = sqrtf(sx2 * (1.0f / CVC)) + 1e-6f;
    gpre[row] = sg + bg[0];
  }
}

// All 4 weight transposes in one launch (2560 blocks, decode per-matrix).
// W[K][N] f32 -> Wt[N][K] bf16.
__global__ void convT_all(const float* __restrict__ Wq_, const float* __restrict__ Wo_,
                          const float* __restrict__ W1_, const float* __restrict__ W2_,
                          __hip_bfloat16* __restrict__ WqT, __hip_bfloat16* __restrict__ WoT,
                          __hip_bfloat16* __restrict__ W1T, __hip_bfloat16* __restrict__ W2T) {
  __shared__ float t[32][33];
  const int id = blockIdx.x;
  const float* W; __hip_bfloat16* Wt; int K, N, bx, by;
  if (id < 256)       { W = Wq_; Wt = WqT; K = 512;  N = 512;  int l = id;        bx = l & 15; by = l >> 4; }
  else if (id < 512)  { W = Wo_; Wt = WoT; K = 512;  N = 512;  int l = id - 256;  bx = l & 15; by = l >> 4; }
  else if (id < 1536) { W = W1_; Wt = W1T; K = 512;  N = 2048; int l = id - 512;  bx = l & 63; by = l >> 6; }
  else                { W = W2_; Wt = W2T; K = 2048; N = 512;  int l = id - 1536; bx = l & 15; by = l >> 4; }
  const int n0 = bx * 32, k0 = by * 32;
  const int tx = threadIdx.x, ty = threadIdx.y;   // 32, 8
  #pragma unroll
  for (int i = 0; i < 32; i += 8) t[ty + i][tx] = W[(size_t)(k0 + ty + i) * N + n0 + tx];
  __syncthreads();
  #pragma unroll
  for (int i = 0; i < 32; i += 8)
    Wt[(size_t)(n0 + ty + i) * K + k0 + tx] = __float2bfloat16(t[tx][ty + i]);
}

// MFMA bf16 GEMM: C[M,N] = A[M,K] @ Bt[N,K]^T + bias
// 256x256 tile, BK=64, 8 waves (2x4), 4-phase-per-K-tile schedule with counted
// vmcnt (never drains to 0 until the LAST tile), T2 XOR-swizzled LDS (inverse swizzle
// applied to global source; global_load_lds writes linearly), T5 setprio.
// EPI 1: sigmoid-gelu -> bf16 (LDS-coalesced) | 2: out += v (LDS-coalesced f32 RMW)
// EPI 3: bf16 store (LDS-coalesced) + per-row partial sum-of-squares of the exact
//        f32 values -> ps[(bn>>8)*4+wn][row] (8 disjoint partials/row, no atomics).
template<int EPI>
__global__ __launch_bounds__(512, 2)
void mfma_gemm(const __hip_bfloat16* __restrict__ A, const __hip_bfloat16* __restrict__ Bt,
               const float* __restrict__ bias, float* __restrict__ out,
               __hip_bfloat16* __restrict__ outbf, float* __restrict__ ps,
               int M, int N, int K) {
  __shared__ __align__(16) char lds[131072];   // A: 2 x 32KB @0, B: 2 x 32KB @64KB
  const int tid = threadIdx.x;
  const int lane = tid & 63;
  const int wid  = tid >> 6;

  // XCD-aware bijective swizzle (all launches have nwg % 8 == 0)
  const int nwg  = gridDim.x * gridDim.y;
  const int orig = blockIdx.y * gridDim.x + blockIdx.x;
  const int wg   = (orig & 7) * (nwg >> 3) + (orig >> 3);
  const int bx = wg % gridDim.x;
  const int by = wg / gridDim.x;
  const int bm = by * 256, bn = bx * 256;

  const int wm = wid >> 2, wn = wid & 3;       // wave -> 128x64 sub-tile
  const int lrow = lane & 15, kq = lane >> 4;

  f32x4 acc[8][4] = {};

  // ---- staging: per gload, lane covers row r_in (of 8) x swizzled 16B block ----
  const int r_in = lane >> 3;                  // 0..7
  const int cblk = (lane & 7) ^ r_in;          // inverse swizzle on global source
  const __hip_bfloat16* gA = A  + (size_t)(bm + r_in) * K + cblk * 8;
  const __hip_bfloat16* gB = Bt + (size_t)(bn + r_in) * K + cblk * 8;
  char* ldsA = lds;
  char* ldsB = lds + 65536;

  auto stageA = [&](int buf, int k0, int half) {
    #pragma unroll
    for (int j = 0; j < 2; j++) {
      int R0 = half * 128 + wid * 16 + j * 8;
      gload_lds16(gA + (size_t)R0 * K + k0, ldsA + buf * 32768 + R0 * 128);
    }
  };
  auto stageB = [&](int buf, int k0, int half) {
    #pragma unroll
    for (int j = 0; j < 2; j++) {
      int R0 = half * 128 + wid * 16 + j * 8;
      gload_lds16(gB + (size_t)R0 * K + k0, ldsB + buf * 32768 + R0 * 128);
    }
  };

  // ---- swizzled LDS reads: blk = (kk*4+kq) ^ (row&7), row&7 == lrow&7 ----
  const int swz = lrow & 7;
  auto ldA = [&](int buf, int m, int kk) -> bf16x8 {
    int r = wm * 128 + m * 16 + lrow;
    int blk = (kk * 4 + kq) ^ swz;
    return *(const bf16x8*)(ldsA + buf * 32768 + r * 128 + blk * 16);
  };
  auto ldB = [&](int buf, int n, int kk) -> bf16x8 {
    int r = wn * 64 + n * 16 + lrow;
    int blk = (kk * 4 + kq) ^ swz;
    return *(const bf16x8*)(ldsB + buf * 32768 + r * 128 + blk * 16);
  };

  const int NT = K >> 6;
  // prologue issue order must match steady-state: B(0), A(0), B(1)  (12 loads)
  stageB(0, 0, 0); stageB(0, 0, 1);
  stageA(0, 0, 0); stageA(0, 0, 1);
  stageB(1, 64, 0); stageB(1, 64, 1);

  bf16x8 af[4][2], bfv[4][2];
  for (int t = 0; t < NT; ++t) {
    const int cur = t & 1;
    // ---- B1: tile t fully landed. Steady state: allow B(t+1) (4 loads) in flight.
    //      Last tile: nothing newer was staged -> full drain. ----
    if (t < NT - 1) {
      asm volatile("s_waitcnt vmcnt(4)" ::: "memory");
    } else {
      asm volatile("s_waitcnt vmcnt(0)" ::: "memory");
    }
    __builtin_amdgcn_s_barrier();
    asm volatile("" ::: "memory");

    // ph0: read af m0..3 + bf n0..1; stage A(t+1) half0; MFMA quadrant (m0-3, n0-1)
    #pragma unroll
    for (int m = 0; m < 4; m++) { af[m][0] = ldA(cur, m, 0); af[m][1] = ldA(cur, m, 1); }
    #pragma unroll
    for (int n = 0; n < 2; n++) { bfv[n][0] = ldB(cur, n, 0); bfv[n][1] = ldB(cur, n, 1); }
    if (t + 1 < NT) stageA(cur ^ 1, (t + 1) << 6, 0);
    __builtin_amdgcn_s_setprio(1);
    #pragma unroll
    for (int m = 0; m < 4; m++)
      #pragma unroll
      for (int n = 0; n < 2; n++) {
        acc[m][n] = __builtin_amdgcn_mfma_f32_16x16x32_bf16(af[m][0], bfv[n][0], acc[m][n], 0, 0, 0);
        acc[m][n] = __builtin_amdgcn_mfma_f32_16x16x32_bf16(af[m][1], bfv[n][1], acc[m][n], 0, 0, 0);
      }
    __builtin_amdgcn_s_setprio(0);

    // ph1: read bf n2..3; stage A(t+1) half1; MFMA quadrant (m0-3, n2-3)
    #pragma unroll
    for (int n = 2; n < 4; n++) { bfv[n][0] = ldB(cur, n, 0); bfv[n][1] = ldB(cur, n, 1); }
    if (t + 1 < NT) stageA(cur ^ 1, (t + 1) << 6, 1);
    __builtin_amdgcn_s_setprio(1);
    #pragma unroll
    for (int m = 0; m < 4; m++)
      #pragma unroll
      for (int n = 2; n < 4; n++) {
        acc[m][n] = __builtin_amdgcn_mfma_f32_16x16x32_bf16(af[m][0], bfv[n][0], acc[m][n], 0, 0, 0);
        acc[m][n] = __builtin_amdgcn_mfma_f32_16x16x32_bf16(af[m][1], bfv[n][1], acc[m][n], 0, 0, 0);
      }
    __builtin_amdgcn_s_setprio(0);

    // ---- B2: all waves' B-slot reads COMPLETE (lgkm drained) before restage ----
    asm volatile("s_waitcnt lgkmcnt(0)" ::: "memory");
    __builtin_amdgcn_s_barrier();
    asm volatile("" ::: "memory");

    // ph2: read af m4..7; stage B(t+2) half0 into cur buf; MFMA (m4-7, n0-1)
    #pragma unroll
    for (int m = 0; m < 4; m++) { af[m][0] = ldA(cur, m + 4, 0); af[m][1] = ldA(cur, m + 4, 1); }
    if (t + 2 < NT) stageB(cur, (t + 2) << 6, 0);
    __builtin_amdgcn_s_setprio(1);
    #pragma unroll
    for (int m = 0; m < 4; m++)
      #pragma unroll
      for (int n = 0; n < 2; n++) {
        acc[m + 4][n] = __builtin_amdgcn_mfma_f32_16x16x32_bf16(af[m][0], bfv[n][0], acc[m + 4][n], 0, 0, 0);
        acc[m + 4][n] = __builtin_amdgcn_mfma_f32_16x16x32_bf16(af[m][1], bfv[n][1], acc[m + 4][n], 0, 0, 0);
      }
    __builtin_amdgcn_s_setprio(0);

    // ph3: stage B(t+2) half1; MFMA (m4-7, n2-3)
    if (t + 2 < NT) stageB(cur, (t + 2) << 6, 1);
    __builtin_amdgcn_s_setprio(1);
    #pragma unroll
    for (int m = 0; m < 4; m++)
      #pragma unroll
      for (int n = 2; n < 4; n++) {
        acc[m + 4][n] = __builtin_amdgcn_mfma_f32_16x16x32_bf16(af[m][0], bfv[n][0], acc[m + 4][n], 0, 0, 0);
        acc[m + 4][n] = __builtin_amdgcn_mfma_f32_16x16x32_bf16(af[m][1], bfv[n][1], acc[m + 4][n], 0, 0, 0);
      }
    __builtin_amdgcn_s_setprio(0);
    // no barrier here: next iteration opens with vmcnt+barrier (B1)
  }

  // epilogue: fragment row = kq*4 + rg, col = lrow
  const int c0 = bn + wn * 64 + lrow;
  if (EPI == 1) {
    // bf16 output via per-wave 16KB LDS (kq-swizzled, conflict-free), 16B/lane stores.
    // gelu: sigmoid form, max |err vs exact| ~5e-4 << bf16 quantization of H.
    __syncthreads();                    // K-loop LDS fully dead
    char* eb = lds + wid * 16384;       // 128 rows x 128B
    #pragma unroll
    for (int n = 0; n < 4; n++) {
      float bval = bias[c0 + n * 16];
      #pragma unroll
      for (int m = 0; m < 8; m++) {
        #pragma unroll
        for (int rg = 0; rg < 4; rg++) {
          int lr  = m * 16 + kq * 4 + rg;               // (lr>>2)&3 == kq
          int lcb = (n * 32 + lrow * 2) ^ (kq << 5);    // swizzled byte-in-row
          float v = acc[m][n][rg] + bval;
          float ge = v / (1.0f + __expf(v * (-1.5957691216f - 0.0713548162f * v * v)));
          *(__hip_bfloat16*)(eb + lr * 128 + lcb) = __float2bfloat16(ge);
        }
      }
    }
    asm volatile("s_waitcnt lgkmcnt(0)" ::: "memory");  // wave-local LDS drain
    __builtin_amdgcn_sched_barrier(0);
    const int rr = lane >> 3, bb = lane & 7;
    #pragma unroll
    for (int it = 0; it < 16; it++) {
      int lr  = it * 8 + rr;
      int lcb = (bb << 4) ^ (((lr >> 2) & 3) << 5);
      uint4 v = *(const uint4*)(eb + lr * 128 + lcb);
      size_t go = (size_t)(bm + wm * 128 + lr) * N + (bn + wn * 64 + bb * 8);
      *(uint4*)(&outbf[go]) = v;
    }
  } else if (EPI == 3) {
    // bf16 output + exact-f32 per-row partial sum of squares.
    __syncthreads();                    // K-loop LDS fully dead
    char* eb = lds + wid * 16384;       // 128 rows x 128B
    float bv4[4];
    #pragma unroll
    for (int n = 0; n < 4; n++) bv4[n] = bias[c0 + n * 16];
    const int psi = (bn >> 8) * 4 + wn; // 8 disjoint partials per row (N=512 only)
    #pragma unroll
    for (int m = 0; m < 8; m++) {
      #pragma unroll
      for (int rg = 0; rg < 4; rg++) {
        int lr = m * 16 + kq * 4 + rg;
        float ss = 0.f;
        #pragma unroll
        for (int n = 0; n < 4; n++) {
          float v = acc[m][n][rg] + bv4[n];
          ss += v * v;
          int lcb = (n * 32 + lrow * 2) ^ (kq << 5);
          *(__hip_bfloat16*)(eb + lr * 128 + lcb) = __float2bfloat16(v);
        }
        // reduce over the 16-lane lrow group (lanes kq*16..kq*16+15)
        ss += __shfl_xor(ss, 1, 64); ss += __shfl_xor(ss, 2, 64);
        ss += __shfl_xor(ss, 4, 64); ss += __shfl_xor(ss, 8, 64);
        if (lrow == 0) ps[(size_t)psi * M + (bm + wm * 128 + lr)] = ss;
      }
    }
    asm volatile("s_waitcnt lgkmcnt(0)" ::: "memory");
    __builtin_amdgcn_sched_barrier(0);
    const int rr = lane >> 3, bb = lane & 7;
    #pragma unroll
    for (int it = 0; it < 16; it++) {
      int lr  = it * 8 + rr;
      int lcb = (bb << 4) ^ (((lr >> 2) & 3) << 5);
      uint4 v = *(const uint4*)(eb + lr * 128 + lcb);
      size_t go = (size_t)(bm + wm * 128 + lr) * N + (bn + wn * 64 + bb * 8);
      *(uint4*)(&outbf[go]) = v;
    }
  } else {
    // f32 output via per-wave 16KB LDS, two 64-row half-passes (f32 tile = 32KB).
    __syncthreads();                    // K-loop LDS fully dead
    char* eb = lds + wid * 16384;       // 64 rows x 256B
    const int rr = lane >> 4, bb = lane & 15;
    #pragma unroll
    for (int half = 0; half < 2; half++) {
      if (half) {                        // half0 reads done before overwrite
        asm volatile("s_waitcnt lgkmcnt(0)" ::: "memory");
        __builtin_amdgcn_sched_barrier(0);
      }
      #pragma unroll
      for (int n = 0; n < 4; n++) {
        float bval = bias[c0 + n * 16];
        #pragma unroll
        for (int m = 0; m < 4; m++) {
          #pragma unroll
          for (int rg = 0; rg < 4; rg++) {
            int lr  = m * 16 + kq * 4 + rg;             // 0..63
            int byo = (n * 64 + lrow * 4) ^ (kq << 6);  // swizzled byte-in-row
            *(float*)(eb + lr * 256 + byo) = acc[half * 4 + m][n][rg] + bval;
          }
        }
      }
      asm volatile("s_waitcnt lgkmcnt(0)" ::: "memory");
      __builtin_amdgcn_sched_barrier(0);
      #pragma unroll
      for (int it = 0; it < 16; it++) {
        int lr  = it * 4 + rr;
        int byo = (bb * 16) ^ (((lr >> 2) & 3) << 6);
        float4 v4 = *(const float4*)(eb + lr * 256 + byo);
        size_t go = (size_t)(bm + wm * 128 + half * 64 + lr) * N + (bn + wn * 64 + bb * 4);
        if (EPI == 0) {
          *(float4*)(&out[go]) = v4;
        } else {
          const float4 o = *(const float4*)(&out[go]);
          v4.x += o.x; v4.y += o.y; v4.z += o.z; v4.w += o.w;
          *(float4*)(&out[go]) = v4;
        }
      }
    }
  }
}

// Fused K/V projection GEMM (one launch, 160 blocks): by<10 -> K, else V
__global__ void kv2_gemm(const float* __restrict__ A,
                         const float* __restrict__ Wk, const float* __restrict__ bk,
                         const float* __restrict__ Wv, const float* __restrict__ bv,
                         float* __restrict__ KF, float* __restrict__ VF,
                         int M, int K, int N) {
  __shared__ float As[16][68];
  __shared__ float Bs[16][68];
  const bool isV = blockIdx.y >= 10;
  const float* W    = isV ? Wv : Wk;
  const float* bias = isV ? bv : bk;
  float* out        = isV ? VF : KF;
  int tid = threadIdx.x;
  int bm = (isV ? blockIdx.y - 10 : blockIdx.y) * 64, bn = blockIdx.x * 64;
  int ty = tid >> 4, tx = tid & 15;
  float acc[4][4] = {};
  for (int k0 = 0; k0 < K; k0 += 16) {
    #pragma unroll
    for (int i = 0; i < 4; i++) {
      int idx = tid + i * 256;
      int mm = idx >> 4, kk = idx & 15;
      int row = bm + mm;
      As[kk][mm] = (row < M) ? A[(size_t)row * K + k0 + kk] : 0.f;
    }
    #pragma unroll
    for (int i = 0; i < 4; i++) {
      int idx = tid + i * 256;
      int kk = idx >> 6, nn = idx & 63;
      Bs[kk][nn] = W[(size_t)(k0 + kk) * N + bn + nn];
    }
    __syncthreads();
    #pragma unroll
    for (int kk = 0; kk < 16; kk++) {
      float4 av = *(const float4*)&As[kk][ty * 4];
      float4 bv4 = *(const float4*)&Bs[kk][tx * 4];
      float a_[4] = {av.x, av.y, av.z, av.w};
      float b_[4] = {bv4.x, bv4.y, bv4.z, bv4.w};
      #pragma unroll
      for (int i = 0; i < 4; i++)
        #pragma unroll
        for (int j = 0; j < 4; j++)
          acc[i][j] = fmaf(a_[i], b_[j], acc[i][j]);
    }
    __syncthreads();
  }
  #pragma unroll
  for (int i = 0; i < 4; i++) {
    int row = bm + ty * 4 + i;
    if (row >= M) continue;
    #pragma unroll
    for (int j = 0; j < 4; j++) {
      int col = bn + tx * 4 + j;
      out[(size_t)row * N + col] = acc[i][j] + bias[col];
    }
  }
}

// Fused K-norm + pad + repack into per-(b,h) MFMA B^T tiles (bf16), t>=77 zero.
// Wave-per-row; lane's 8 cols all belong to head lane>>3 -> 16B contiguous store.
__global__ __launch_bounds__(256)
void kprep_kernel(const float* __restrict__ kf, const float* __restrict__ text,
                  __hip_bfloat16* __restrict__ kbf, int* __restrict__ pad) {
  const int lane = threadIdx.x & 63;
  const int row  = blockIdx.x * 4 + (threadIdx.x >> 6);   // 0..615
  if (blockIdx.x == 0) {
    // zero-fill t=77..79 for all 64 (b,h) tiles (disjoint from t<77 writes)
    for (int i = threadIdx.x; i < 64 * 3 * 64; i += 256) {
      int bh = i / 192, rem = i % 192, tt = 77 + rem / 64, d = rem & 63;
      kbf[(size_t)bh * (80 * 64) + tt * 64 + d] = __float2bfloat16(0.f);
    }
  }
  const float* p  = kf + (size_t)row * CVC + lane * 8;
  const float* tx = text + (size_t)row * CVC + lane * 8;
  float4 va = *(const float4*)p;
  float4 vb = *(const float4*)(p + 4);
  float4 ta = *(const float4*)tx;
  float4 tb = *(const float4*)(tx + 4);
  float v[8] = {va.x, va.y, va.z, va.w, vb.x, vb.y, vb.z, vb.w};
  float t[8] = {ta.x, ta.y, ta.z, ta.w, tb.x, tb.y, tb.z, tb.w};
  float s = 0.f, a = 0.f;
  #pragma unroll
  for (int i = 0; i < 8; i++) { s += v[i] * v[i]; a += fabsf(t[i]); }
  s = wave_reduce_sum(s);
  a = wave_reduce_sum(a);
  float inv = 1.0f / fmaxf(sqrtf(s), 1e-6f);
  const int b = row / T77, tt = row - b * T77;
  const int h = lane >> 3, d0 = (lane & 7) * 8;
  union { bf16x8 v8; __hip_bfloat16 h8[8]; } u;
  #pragma unroll
  for (int i = 0; i < 8; i++) u.h8[i] = __float2bfloat16(v[i] * inv);
  *(bf16x8*)(kbf + ((size_t)(b * 8 + h) * 80 + tt) * 64 + d0) = u.v8;
  if (lane == 0) pad[row] = (a <= 1e-6f) ? 1 : 0;
}

// Attention phase A: SIM[row][h][t] = qfull_row_h . k_t_h via MFMA (raw dot;
// per-row 1/||q|| is folded into attnB's scale — scaling commutes with top-k).
__global__ __launch_bounds__(256)
void simA_kernel(const __hip_bfloat16* __restrict__ qbf, const __hip_bfloat16* __restrict__ kbf,
                 float* __restrict__ sim) {
  const int tid = threadIdx.x;
  const int wid = tid >> 6, lane = tid & 63;
  const int r0 = blockIdx.x * 64 + wid * 16;     // 16 rows per wave
  const int b = (blockIdx.x * 64) >> 12;         // 4096 rows per batch
  const int lrow = lane & 15, kq = lane >> 4;
  const __hip_bfloat16* qrow = qbf + (size_t)(r0 + lrow) * CVC;
  for (int h = 0; h < HHC; h++) {
    const __hip_bfloat16* kb = kbf + (size_t)(b * 8 + h) * (80 * 64);
    f32x4 acc[5] = {};
    #pragma unroll
    for (int ks = 0; ks < 2; ks++) {
      bf16x8 af = *(const bf16x8*)(qrow + h * DHC + ks * 32 + kq * 8);
      #pragma unroll
      for (int n = 0; n < 5; n++) {
        bf16x8 bf = *(const bf16x8*)(kb + (size_t)(n * 16 + lrow) * DHC + ks * 32 + kq * 8);
        acc[n] = __builtin_amdgcn_mfma_f32_16x16x32_bf16(af, bf, acc[n], 0, 0, 0);
      }
    }
    // C layout: row = r0 + kq*4 + reg, col = n*16 + lrow
    #pragma unroll
    for (int n = 0; n < 5; n++)
      #pragma unroll
      for (int rg = 0; rg < 4; rg++)
        sim[(size_t)(r0 + kq * 4 + rg) * 640 + h * 80 + n * 16 + lrow] = acc[n][rg];
  }
}

// Attention phase B: per (row,head) thread streams its 80-entry sim row (coalesced),
// applies per-row invq (exact f32 norm from PS partials), top-5 / softmax / nucleus /
// entropy / conf, then cooperative sparse PV -> bf16.
__global__ __launch_bounds__(256)
void attnB_kernel(const float* __restrict__ sim, const float* __restrict__ vf,
                  const int* __restrict__ pad, const float* __restrict__ ls,
                  const float* __restrict__ psq,
                  float* __restrict__ conf_out, __hip_bfloat16* __restrict__ abf) {
  __shared__ float spr[32][HHC][5];
  __shared__ int   sti[32][HHC][5];
  __shared__ float sconf[256];
  __shared__ float sbias[80];
  __shared__ float sinvq[32];
  const int tid = threadIdx.x;
  const int r = tid >> 3, h = tid & 7;
  const int r0 = blockIdx.x * 32;
  const int b = r0 >> 12;
  const float lsv = fminf(fmaxf(ls[0], -2.0f), 2.0f);
  const float scale = expf(lsv) * 0.125f;   // / sqrt(64)

  if (tid < 80) sbias[tid] = (tid < T77 && !pad[b * T77 + tid]) ? 0.0f : -INFINITY;
  if (tid < 32) {
    float s2 = 0.f;
    #pragma unroll
    for (int j = 0; j < 8; j++) s2 += psq[(size_t)j * NROW + r0 + tid];
    sinvq[tid] = 1.0f / fmaxf(sqrtf(s2), 1e-6f);
  }
  __syncthreads();

  const float srow = scale * sinvq[r];
  // stream 80 sim values (20 float4, contiguous per thread, coalesced per block)
  float t0 = -INFINITY, t1 = -INFINITY, t2 = -INFINITY, t3 = -INFINITY, t4 = -INFINITY;
  int   i0 = -1, i1 = -1, i2 = -1, i3 = -1, i4 = -1;
  const float4* simp = (const float4*)(sim + (size_t)(r0 + r) * 640 + h * 80);
  #pragma unroll
  for (int tt = 0; tt < 20; tt++) {
    float4 v4 = simp[tt];
    #pragma unroll
    for (int j = 0; j < 4; j++) {
      int t = tt * 4 + j;
      float sv = (j == 0 ? v4.x : j == 1 ? v4.y : j == 2 ? v4.z : v4.w);
      float s = sv * srow + sbias[t];
      if (s > t4) {
        t4 = s; i4 = t;
        if (t4 > t3) { float f = t3; t3 = t4; t4 = f; int x = i3; i3 = i4; i4 = x; }
        if (t3 > t2) { float f = t2; t2 = t3; t3 = f; int x = i2; i2 = i3; i3 = x; }
        if (t2 > t1) { float f = t1; t1 = t2; t2 = f; int x = i1; i1 = i2; i2 = x; }
        if (t1 > t0) { float f = t0; t0 = t1; t1 = f; int x = i0; i0 = i1; i1 = x; }
      }
    }
  }

  // softmax over top-5
  float e0 = (t0 == -INFINITY) ? 0.f : expf(t0 - t0);
  float e1 = (t1 == -INFINITY) ? 0.f : expf(t1 - t0);
  float e2 = (t2 == -INFINITY) ? 0.f : expf(t2 - t0);
  float e3 = (t3 == -INFINITY) ? 0.f : expf(t3 - t0);
  float e4 = (t4 == -INFINITY) ? 0.f : expf(t4 - t0);
  float invs = 1.0f / (e0 + e1 + e2 + e3 + e4);
  float p0 = e0 * invs, p1 = e1 * invs, p2 = e2 * invs, p3 = e3 * invs, p4 = e4 * invs;
  // nucleus: inclusive cumsum <= 0.9, top-1 forced
  float c1 = p0 + p1, c2 = c1 + p2, c3 = c2 + p3, c4 = c3 + p4;
  bool k1 = (c1 <= 0.9f), k2 = (c2 <= 0.9f), k3 = (c3 <= 0.9f), k4 = (c4 <= 0.9f);
  float skeep = p0 + (k1 ? p1 : 0.f) + (k2 ? p2 : 0.f) + (k3 ? p3 : 0.f) + (k4 ? p4 : 0.f);
  float rn = 1.0f / fmaxf(skeep, 1e-6f);
  float w0 = p0 * rn, w1 = k1 ? p1 * rn : 0.f, w2 = k2 ? p2 * rn : 0.f,
        w3 = k3 ? p3 * rn : 0.f, w4 = k4 ? p4 * rn : 0.f;
  int nnz = (w0 > 0.f) + (w1 > 0.f) + (w2 > 0.f) + (w3 > 0.f) + (w4 > 0.f);
  float ent = 0.f;
  {
    float pc;
    pc = fmaxf(w0, 1e-8f); ent -= pc * logf(pc);
    pc = fmaxf(w1, 1e-8f); ent -= pc * logf(pc);
    pc = fmaxf(w2, 1e-8f); ent -= pc * logf(pc);
    pc = fmaxf(w3, 1e-8f); ent -= pc * logf(pc);
    pc = fmaxf(w4, 1e-8f); ent -= pc * logf(pc);
  }
  ent += (float)(T77 - 5) * 1.8420681e-7f;   // 72 zero entries at pc=1e-8
  float denom = logf(fmaxf(fmaxf((float)nnz, 1.0f), 2.0f));
  ent /= denom;
  float confh = fminf(fmaxf(w0 * (1.0f - ent), 0.f), 1.f);

  spr[r][h][0] = w0; spr[r][h][1] = w1; spr[r][h][2] = w2; spr[r][h][3] = w3; spr[r][h][4] = w4;
  sti[r][h][0] = i0; sti[r][h][1] = i1; sti[r][h][2] = i2; sti[r][h][3] = i3; sti[r][h][4] = i4;
  sconf[tid] = confh;
  __syncthreads();

  if (tid < 32) {
    float s = 0.f;
    #pragma unroll
    for (int j = 0; j < 8; j++) s += sconf[tid * 8 + j];
    conf_out[r0 + tid] = s * 0.125f;
  }

  // cooperative sparse PV: wave-uniform (row,head) -> coalesced v loads
  #pragma unroll
  for (int it = 0; it < 64; it++) {
    int idx = tid + it * 256;
    int rr = idx >> 9, c = idx & 511, hh = c >> 6;
    float a = 0.f;
    #pragma unroll
    for (int i = 0; i < 5; i++) {
      float pr = spr[rr][hh][i]; int t = sti[rr][hh][i];
      if (pr > 0.f && t >= 0) a = fmaf(pr, vf[((size_t)(b * T77 + t)) * CVC + c], a);
    }
    abf[(size_t)(r0 + rr) * CVC + c] = __float2bfloat16(a);
  }
}

// Trust region + gate + residual -> y (f32 out) AND LN2(y) in bf16.
// aligned read as bf16 + exact-f32 sumsq partials (a_norm exact); wave-per-row.
__global__ __launch_bounds__(256)
void combine_kernel(const __hip_bfloat16* __restrict__ alnbf, const float* __restrict__ ps,
                    const float* __restrict__ visual,
                    const float* __restrict__ m1, const float* __restrict__ r1,
                    const float* __restrict__ g1, const float* __restrict__ b1v,
                    const float* __restrict__ xrms, const float* __restrict__ gpre,
                    const float* __restrict__ conf, const float* __restrict__ alpha,
                    const float* __restrict__ g2, const float* __restrict__ b2v,
                    float* __restrict__ dout, __hip_bfloat16* __restrict__ ybf) {
  const int lane = threadIdx.x & 63;
  const int row  = blockIdx.x * 4 + (threadIdx.x >> 6);
  float s2 = 0.f;
  #pragma unroll
  for (int j = 0; j < 8; j++) s2 += ps[(size_t)j * NROW + row];
  float an = sqrtf(s2);
  float factor = fminf(0.5f * xrms[row] / fmaxf(an, 1e-6f), 1.0f);
  float gate = conf[row] / (1.0f + expf(-gpre[row]));
  float coef = alpha[0] * gate * factor;
  float mm = m1[row], rs = r1[row];
  union { bf16x8 v8; __hip_bfloat16 h[8]; } ua;
  ua.v8 = *(const bf16x8*)(alnbf + (size_t)row * CVC + lane * 8);
  float av[8];
  #pragma unroll
  for (int i = 0; i < 8; i++) av[i] = __bfloat162float(ua.h[i]);
  const float* vr = visual + (size_t)row * CVC + lane * 8;
  float4 va = *(const float4*)vr;
  float4 vb = *(const float4*)(vr + 4);
  float v[8] = {va.x, va.y, va.z, va.w, vb.x, vb.y, vb.z, vb.w};
  const float4 ga = *(const float4*)(g1 + lane * 8), gb = *(const float4*)(g1 + lane * 8 + 4);
  const float4 ba = *(const float4*)(b1v + lane * 8), bb2 = *(const float4*)(b1v + lane * 8 + 4);
  float gg[8] = {ga.x, ga.y, ga.z, ga.w, gb.x, gb.y, gb.z, gb.w};
  float bbv[8] = {ba.x, ba.y, ba.z, ba.w, bb2.x, bb2.y, bb2.z, bb2.w};
  float y[8], sy = 0.f;
  #pragma unroll
  for (int i = 0; i < 8; i++) {
    float x = (v[i] - mm) * rs * gg[i] + bbv[i];
    y[i] = x + coef * av[i];
    sy += y[i];
  }
  float* orow = dout + (size_t)row * CVC + lane * 8;
  float4 o0 = {y[0], y[1], y[2], y[3]};
  float4 o1 = {y[4], y[5], y[6], y[7]};
  *(float4*)orow = o0;
  *(float4*)(orow + 4) = o1;
  float ym = wave_reduce_sum(sy) * (1.0f / CVC);
  float var = 0.f;
  #pragma unroll
  for (int i = 0; i < 8; i++) { float d = y[i] - ym; var += d * d; }
  var = wave_reduce_sum(var) * (1.0f / CVC);
  float rs2 = rsqrtf(var + 1e-5f);
  const float4 g2a = *(const float4*)(g2 + lane * 8), g2b = *(const float4*)(g2 + lane * 8 + 4);
  const float4 b2a = *(const float4*)(b2v + lane * 8), b2b = *(const float4*)(b2v + lane * 8 + 4);
  float g2v[8] = {g2a.x, g2a.y, g2a.z, g2a.w, g2b.x, g2b.y, g2b.z, g2b.w};
  float b2vv[8] = {b2a.x, b2a.y, b2a.z, b2a.w, b2b.x, b2b.y, b2b.z, b2b.w};
  union { bf16x8 v8; __hip_bfloat16 h[8]; } u;
  #pragma unroll
  for (int i = 0; i < 8; i++)
    u.h[i] = __float2bfloat16((y[i] - ym) * rs2 * g2v[i] + b2vv[i]);
  *(bf16x8*)(ybf + (size_t)row * CVC + lane * 8) = u.v8;
}

extern "C" void kernel_launch(void* const* d_in, const int* in_sizes, int n_in,
                              void* d_out, int out_size, void* d_ws, size_t ws_size,
                              hipStream_t stream) {
  const float* visual = (const float*)d_in[0];
  const float* text   = (const float*)d_in[1];
  const float* ln1_g  = (const float*)d_in[2];
  const float* ln1_b  = (const float*)d_in[3];
  const float* ln2_g  = (const float*)d_in[4];
  const float* ln2_b  = (const float*)d_in[5];
  const float* Wq = (const float*)d_in[6];  const float* bq = (const float*)d_in[7];
  const float* Wk = (const float*)d_in[8];  const float* bk = (const float*)d_in[9];
  const float* Wv = (const float*)d_in[10]; const float* bv = (const float*)d_in[11];
  const float* Wo = (const float*)d_in[12]; const float* bo = (const float*)d_in[13];
  const float* Wg = (const float*)d_in[14]; const float* bg = (const float*)d_in[15];
  const float* W1 = (const float*)d_in[16]; const float* b1 = (const float*)d_in[17];
  const float* W2 = (const float*)d_in[18]; const float* b2 = (const float*)d_in[19];
  const float* ls    = (const float*)d_in[20];
  const float* alpha = (const float*)d_in[21];
  float* out = (float*)d_out;

  // ws layout (base region, sequential lifetimes):
  //   QBF2 bf16 @0 (32MB, Wq out, live -> simA)
  //   SIM f32 @32MB (84MB, live simA -> attnB)   [no overlap with QBF2]
  //   ALNBF bf16 @0 (32MB, Wo out, live -> combine)
  //   H bf16 @0 (128MB, MLP stage)
  // [128,160MiB): CBF bf16 [32768][512]: XBF -> ABF -> YBF (sequential)
  // [160MiB...): weight transposes, K/V, pad, per-row stats, KBF, PS partials
  char* base = (char*)d_ws;
  __hip_bfloat16* QBF2  = (__hip_bfloat16*)base;
  __hip_bfloat16* ALNBF = (__hip_bfloat16*)base;
  __hip_bfloat16* H     = (__hip_bfloat16*)base;
  float* SIM  = (float*)(base + ((size_t)32 << 20));
  __hip_bfloat16* CBF = (__hip_bfloat16*)(base + ((size_t)128 << 20));
  char* p = base + ((size_t)160 << 20);
  __hip_bfloat16* WqT = (__hip_bfloat16*)p; p += (size_t)512 * 512 * 2;
  __hip_bfloat16* WoT = (__hip_bfloat16*)p; p += (size_t)512 * 512 * 2;
  __hip_bfloat16* W1T = (__hip_bfloat16*)p; p += (size_t)2048 * 512 * 2;
  __hip_bfloat16* W2T = (__hip_bfloat16*)p; p += (size_t)512 * 2048 * 2;
  float* KF = (float*)p; p += (size_t)BT * CVC * 4;
  float* VF = (float*)p; p += (size_t)BT * CVC * 4;
  int* PADF = (int*)p;  p += 4096;
  float* MEAN1 = (float*)p; p += (size_t)NROW * 4;
  float* RSTD1 = (float*)p; p += (size_t)NROW * 4;
  float* XRMS  = (float*)p; p += (size_t)NROW * 4;
  float* GPRE  = (float*)p; p += (size_t)NROW * 4;
  float* CONF  = (float*)p; p += (size_t)NROW * 4;
  __hip_bfloat16* KBF = (__hip_bfloat16*)p; p += (size_t)64 * 80 * 64 * 2;
  float* PS = (float*)p; p += (size_t)8 * NROW * 4;   // Wq->attnB, then Wo->combine

  stats1_kernel<<<NROW / 4, 256, 0, stream>>>(visual, ln1_g, ln1_b, Wg, bg,
                                              MEAN1, RSTD1, XRMS, GPRE, CBF);
  convT_all<<<2560, dim3(32, 8), 0, stream>>>(Wq, Wo, W1, W2, WqT, WoT, W1T, W2T);

  // q_full = x_bf @ Wq + bq  (bf16 out, unnormalized + exact-f32 row sumsq partials)
  mfma_gemm<3><<<dim3(2, 128), 512, 0, stream>>>(CBF, WqT, bq, nullptr, QBF2, PS,
                                                 NROW, 512, 512);

  kv2_gemm<<<dim3(8, 20), 256, 0, stream>>>(text, Wk, bk, Wv, bv, KF, VF, BT, CVC, CVC);
  kprep_kernel<<<BT / 4, 256, 0, stream>>>(KF, text, KBF, PADF);

  // attention phase A: SIM = qfull . k (raw; invq folded into attnB)
  simA_kernel<<<NROW / 64, 256, 0, stream>>>(QBF2, KBF, SIM);
  // attention phase B: invq-scale/select/softmax/nucleus/entropy/PV -> ABF (CBF)
  attnB_kernel<<<NROW / 32, 256, 0, stream>>>(SIM, VF, PADF, ls, PS, CONF, CBF);

  // aligned1 = aligned0 @ Wo + bo (bf16 out + exact sumsq partials; SIM/QBF2 dead)
  mfma_gemm<3><<<dim3(2, 128), 512, 0, stream>>>(CBF, WoT, bo, nullptr, ALNBF, PS,
                                                 NROW, 512, 512);

  // y -> out (f32), LN2(y) -> CBF bf16 (ABF dead)
  combine_kernel<<<NROW / 4, 256, 0, stream>>>(ALNBF, PS, visual, MEAN1, RSTD1, ln1_g, ln1_b,
                                               XRMS, GPRE, CONF, alpha, ln2_g, ln2_b, out, CBF);

  // h = gelu(LN2(y) @ W1 + b1) -> bf16 H (ALNBF dead)
  mfma_gemm<1><<<dim3(8, 128), 512, 0, stream>>>(CBF, W1T, b1, nullptr, H, nullptr,
                                                 NROW, 2048, 512);

  // out = y + h @ W2 + b2
  mfma_gemm<2><<<dim3(2, 128), 512, 0, stream>>>(H, W2T, b2, out, nullptr, nullptr,
                                                 NROW, 512, 2048);
}